// Round 11
// baseline (737.379 us; speedup 1.0000x reference)
//
#include <hip/hip_runtime.h>

typedef unsigned short u16;
typedef unsigned int   u32;
typedef __attribute__((ext_vector_type(8))) short bf16x8;
typedef __attribute__((ext_vector_type(4))) float f32x4;

#define L_TOK   16384
#define C_DIM   192
#define HID_DIM 768

// bf16 weight workspace layout (u16 offsets)
#define OFF_QKV  0          // qkvwT[head][cc=grp*32+dim][k]   6*96*192   = 110592
#define OFF_PROJ 110592     // projT [head][c][j]              6*192*32   =  36864
#define OFF_FC1  147456     // fc1wT [h][k]                    768*192    = 147456
#define OFF_FC2  294912     // fc2wT [c][h]                    192*768    = 147456
#define CVT_TOT  442368     // total u16 elements (884736 B)

union FragU { int4 i4; bf16x8 h8; };

#define MFMA_B16(a,b,c) __builtin_amdgcn_mfma_f32_16x16x32_bf16(a,b,c,0,0,0)

__device__ __forceinline__ u16 f2bf(float f) {
    u32 t; __builtin_memcpy(&t, &f, 4);
    t += 0x7FFFu + ((t >> 16) & 1u);
    return (u16)(t >> 16);
}

// ---------------------------------------------------------------------------
// Kernel 0 v2: f32 -> bf16 weight convert+transpose, SOURCE-coalesced.
// ---------------------------------------------------------------------------
__global__ __launch_bounds__(256) void k_cvt(
    const float* __restrict__ qkvw, const float* __restrict__ projw,
    const float* __restrict__ fc1w, const float* __restrict__ fc2w,
    u16* __restrict__ ws)
{
    const int i = blockIdx.x * 256 + threadIdx.x;
    if (i >= CVT_TOT) return;
    float v; int dst;
    if (i < OFF_PROJ) {                      // qkvw[k][col], k=i/576
        const int k = i / 576, col = i % 576;
        const int grp = col / 192, rem = col % 192;
        const int head = rem >> 5, dim = rem & 31;
        v = qkvw[i];
        dst = OFF_QKV + head * (96 * 192) + (grp * 32 + dim) * 192 + k;
    } else if (i < OFF_FC1) {                // projw[cin][cout]
        const int s = i - OFF_PROJ;
        const int cin = s / 192, cout = s % 192;
        const int head = cin >> 5, j = cin & 31;
        v = projw[s];
        dst = OFF_PROJ + head * (192 * 32) + cout * 32 + j;
    } else if (i < OFF_FC2) {                // fc1w[k][h]
        const int s = i - OFF_FC1;
        const int k = s / 768, h = s % 768;
        v = fc1w[s];
        dst = OFF_FC1 + h * 192 + k;
    } else {                                 // fc2w[h][c]
        const int s = i - OFF_FC2;
        const int h = s / 192, c = s % 192;
        v = fc2w[s];
        dst = OFF_FC2 + c * 768 + h;
    }
    ws[dst] = f2bf(v);
}

// ---------------------------------------------------------------------------
// Kernel 1 v4 (R8, best-known): two windows per block + register-prefetched
// weight staging. LDS ~79.1KB -> 2 blocks/CU. UNCHANGED.
// ---------------------------------------------------------------------------
__global__ __launch_bounds__(256, 2) void k_attnproj(
    const float* __restrict__ x, const float* __restrict__ g1v, const float* __restrict__ b1v,
    const u16* __restrict__ qkvwT, const float* __restrict__ qkvb,
    const float* __restrict__ relb, const u16* __restrict__ projT, const float* __restrict__ projb,
    float* __restrict__ x1)
{
    struct PW {
        u16 qsb[64 * 40];
        u16 ksb[64 * 40];
        u16 vsbT[32 * 72];
        u16 psb[64 * 72];
        u16 oh [64 * 40];
    };                                      // 29184 B per window
    union SmemU {
        u16 xw[128 * 200];                  // 51200 B (phase A only, padded stride)
        PW pw[2];                           // 58368 B
    };
    __shared__ __align__(16) SmemU u;
    __shared__ __align__(16) u16 wbuf[192 * 40];   // 15360 B
    __shared__ float relbs[225 * 6];               //  5400 B

    const int t  = threadIdx.x;
    const int lane = t & 63, w = t >> 6;
    const int win = w >> 1, half = w & 1;
    const int l15 = lane & 15, quad = lane >> 4;
    const int wi2 = blockIdx.x * 2 + win;
    const int b  = wi2 >> 8;
    const int hb = (wi2 >> 4) & 15;
    const int wb = wi2 & 15;
    const bool maskon = (hb == 15) || (wb == 15);
    const f32x4 zf = {0.f, 0.f, 0.f, 0.f};

    for (int i = t; i < 225 * 6; i += 256) relbs[i] = relb[i];

    #pragma unroll
    for (int tk = 0; tk < 2; ++tk) {
        const int nn = t >> 2, q4 = t & 3;
        const int tok = tk * 64 + nn;
        const int tw = tok >> 6, n = tok & 63;
        const int wiA = blockIdx.x * 2 + tw;
        const int bA  = wiA >> 8;
        const int hbA = (wiA >> 4) & 15, wbA = wiA & 15;
        const int r = n >> 3, c = n & 7;
        const int ho = (hbA * 8 + r + 4) & 127;
        const int wo = (wbA * 8 + c + 4) & 127;
        const size_t xoff = ((size_t)bA * L_TOK + ho * 128 + wo) * C_DIM;
        const float* xp = x + xoff + q4 * 48;
        float f[48];
        float sum = 0.f, sq = 0.f;
        #pragma unroll
        for (int i = 0; i < 12; ++i) {
            float4 v = *(const float4*)(xp + i * 4);
            f[i*4+0]=v.x; f[i*4+1]=v.y; f[i*4+2]=v.z; f[i*4+3]=v.w;
            sum += v.x+v.y+v.z+v.w;
            sq  += v.x*v.x + v.y*v.y + v.z*v.z + v.w*v.w;
        }
        sum += __shfl_xor(sum, 1); sum += __shfl_xor(sum, 2);
        sq  += __shfl_xor(sq, 1);  sq  += __shfl_xor(sq, 2);
        const float mu = sum * (1.f / 192.f);
        const float rstd = rsqrtf(sq * (1.f / 192.f) - mu * mu + 1e-5f);
        u16* xrow = u.xw + tok * 200 + q4 * 48;
        #pragma unroll
        for (int i = 0; i < 6; ++i) {
            u32 pk[4];
            #pragma unroll
            for (int j = 0; j < 4; ++j) {
                float g0 = g1v[q4*48 + i*8 + j*2],     b0 = b1v[q4*48 + i*8 + j*2];
                float g1 = g1v[q4*48 + i*8 + j*2 + 1], b1 = b1v[q4*48 + i*8 + j*2 + 1];
                float y0 = (f[i*8+j*2]   - mu) * rstd * g0 + b0;
                float y1 = (f[i*8+j*2+1] - mu) * rstd * g1 + b1;
                pk[j] = (u32)f2bf(y0) | (((u32)f2bf(y1)) << 16);
            }
            *(int4*)(xrow + i * 8) = make_int4((int)pk[0], (int)pk[1], (int)pk[2], (int)pk[3]);
        }
    }
    __syncthreads();

    FragU afrag[2][6];
    #pragma unroll
    for (int mt = 0; mt < 2; ++mt)
        #pragma unroll
        for (int kk = 0; kk < 6; ++kk)
            afrag[mt][kk].i4 = *(const int4*)(u.xw +
                (win*64 + half*32 + mt*16 + l15) * 200 + kk*32 + quad*8);

    PW* P = &u.pw[win];
    const int rb = half*32 + quad*4;

    int4 wr0, wr1, wr2;
    auto LOADW = [&](int hh, int sub) {
        if (sub < 3) {
            const u16* src = qkvwT + (size_t)hh * (96 * 192) + sub * 64;
            wr0 = *(const int4*)(src + ((t      ) >> 3) * 192 + ((t      ) & 7) * 8);
            wr1 = *(const int4*)(src + ((t + 256) >> 3) * 192 + ((t + 256) & 7) * 8);
            wr2 = *(const int4*)(src + ((t + 512) >> 3) * 192 + ((t + 512) & 7) * 8);
        } else {
            const u16* src = projT + (size_t)hh * (192 * 32);
            wr0 = *(const int4*)(src + ((t      ) >> 2) * 32 + ((t      ) & 3) * 8);
            wr1 = *(const int4*)(src + ((t + 256) >> 2) * 32 + ((t + 256) & 3) * 8);
            wr2 = *(const int4*)(src + ((t + 512) >> 2) * 32 + ((t + 512) & 3) * 8);
        }
    };
    auto STOREW = [&](int sub) {
        if (sub < 3) {
            *(int4*)(wbuf + ((t      ) >> 3) * 72 + ((t      ) & 7) * 8) = wr0;
            *(int4*)(wbuf + ((t + 256) >> 3) * 72 + ((t + 256) & 7) * 8) = wr1;
            *(int4*)(wbuf + ((t + 512) >> 3) * 72 + ((t + 512) & 7) * 8) = wr2;
        } else {
            *(int4*)(wbuf + ((t      ) >> 2) * 40 + ((t      ) & 3) * 8) = wr0;
            *(int4*)(wbuf + ((t + 256) >> 2) * 40 + ((t + 256) & 3) * 8) = wr1;
            *(int4*)(wbuf + ((t + 512) >> 2) * 40 + ((t + 512) & 3) * 8) = wr2;
        }
    };
    LOADW(0, 0);

    f32x4 acc2[2][12];
    #pragma unroll
    for (int mt = 0; mt < 2; ++mt)
        #pragma unroll
        for (int nt = 0; nt < 12; ++nt) acc2[mt][nt] = zf;

    for (int head = 0; head < 6; ++head) {
        f32x4 accq[2][6];
        #pragma unroll
        for (int mt = 0; mt < 2; ++mt)
            #pragma unroll
            for (int nt = 0; nt < 6; ++nt) accq[mt][nt] = zf;

        for (int kc = 0; kc < 3; ++kc) {
            __syncthreads();
            STOREW(kc);
            __syncthreads();
            LOADW(head, kc + 1);
            #pragma unroll
            for (int s = 0; s < 2; ++s) {
                #pragma unroll
                for (int nt = 0; nt < 6; ++nt) {
                    FragU bf_;
                    bf_.i4 = *(const int4*)(wbuf + (nt*16 + l15)*72 + s*32 + quad*8);
                    accq[0][nt] = MFMA_B16(afrag[0][kc*2 + s].h8, bf_.h8, accq[0][nt]);
                    accq[1][nt] = MFMA_B16(afrag[1][kc*2 + s].h8, bf_.h8, accq[1][nt]);
                }
            }
        }
        #pragma unroll
        for (int mt = 0; mt < 2; ++mt) {
            #pragma unroll
            for (int nt = 0; nt < 6; ++nt) {
                const int grp = nt >> 1;
                const int dim = (nt & 1)*16 + l15;
                const float bias = qkvb[grp*192 + head*32 + dim];
                float vv[4];
                #pragma unroll
                for (int rg = 0; rg < 4; ++rg) vv[rg] = accq[mt][nt][rg] + bias;
                const int rowb = rb + mt*16;
                if (grp == 0) {
                    #pragma unroll
                    for (int rg = 0; rg < 4; ++rg)
                        P->qsb[(rowb + rg)*40 + dim] = f2bf(vv[rg] * 0.17677669529663687f);
                } else if (grp == 1) {
                    #pragma unroll
                    for (int rg = 0; rg < 4; ++rg)
                        P->ksb[(rowb + rg)*40 + dim] = f2bf(vv[rg]);
                } else {
                    u32 lo = (u32)f2bf(vv[0]) | (((u32)f2bf(vv[1])) << 16);
                    u32 hi = (u32)f2bf(vv[2]) | (((u32)f2bf(vv[3])) << 16);
                    *(uint2*)&P->vsbT[dim*72 + rowb] = make_uint2(lo, hi);
                }
            }
        }
        __syncthreads();

        FragU qf0, qf1;
        qf0.i4 = *(const int4*)(P->qsb + (half*32 + l15)*40 + quad*8);
        qf1.i4 = *(const int4*)(P->qsb + (half*32 + 16 + l15)*40 + quad*8);
        f32x4 sv[2][4];
        #pragma unroll
        for (int nt = 0; nt < 4; ++nt) {
            FragU kf; kf.i4 = *(const int4*)(P->ksb + (nt*16 + l15)*40 + quad*8);
            sv[0][nt] = MFMA_B16(qf0.h8, kf.h8, zf);
            sv[1][nt] = MFMA_B16(qf1.h8, kf.h8, zf);
        }
        const int kr_ = l15 >> 3, kc2 = l15 & 7;
        #pragma unroll
        for (int mt = 0; mt < 2; ++mt) {
            #pragma unroll
            for (int rg = 0; rg < 4; ++rg) {
                const int qm = rb + mt*16 + rg;
                const int qr = qm >> 3, qc = qm & 7;
                #pragma unroll
                for (int nt = 0; nt < 4; ++nt) {
                    const int kr = nt*2 + kr_;
                    sv[mt][nt][rg] += relbs[((qr - kr + 7)*15 + (qc - kc2 + 7))*6 + head];
                }
            }
        }
        if (maskon) {
            #pragma unroll
            for (int mt = 0; mt < 2; ++mt) {
                #pragma unroll
                for (int rg = 0; rg < 4; ++rg) {
                    const int qm = rb + mt*16 + rg;
                    const int qr = qm >> 3, qc = qm & 7;
                    const int regq = ((hb == 15) ? (qr < 4 ? 1 : 2) : 0) * 3
                                   + ((wb == 15) ? (qc < 4 ? 1 : 2) : 0);
                    #pragma unroll
                    for (int nt = 0; nt < 4; ++nt) {
                        const int kr = nt*2 + kr_;
                        const int regk = ((hb == 15) ? (kr < 4 ? 1 : 2) : 0) * 3
                                       + ((wb == 15) ? (kc2 < 4 ? 1 : 2) : 0);
                        if (regq != regk) sv[mt][nt][rg] -= 100.f;
                    }
                }
            }
        }
        #pragma unroll
        for (int mt = 0; mt < 2; ++mt) {
            #pragma unroll
            for (int rg = 0; rg < 4; ++rg) {
                float mx = fmaxf(fmaxf(sv[mt][0][rg], sv[mt][1][rg]),
                                 fmaxf(sv[mt][2][rg], sv[mt][3][rg]));
                mx = fmaxf(mx, __shfl_xor(mx, 1));
                mx = fmaxf(mx, __shfl_xor(mx, 2));
                mx = fmaxf(mx, __shfl_xor(mx, 4));
                mx = fmaxf(mx, __shfl_xor(mx, 8));
                float s0 = 0.f;
                #pragma unroll
                for (int nt = 0; nt < 4; ++nt) {
                    sv[mt][nt][rg] = __expf(sv[mt][nt][rg] - mx); s0 += sv[mt][nt][rg];
                }
                s0 += __shfl_xor(s0, 1); s0 += __shfl_xor(s0, 2);
                s0 += __shfl_xor(s0, 4); s0 += __shfl_xor(s0, 8);
                const float inv = 1.f / s0;
                #pragma unroll
                for (int nt = 0; nt < 4; ++nt)
                    P->psb[(rb + mt*16 + rg)*72 + nt*16 + l15] = f2bf(sv[mt][nt][rg] * inv);
            }
        }

        FragU vb[2][2];
        #pragma unroll
        for (int ntv = 0; ntv < 2; ++ntv) {
            vb[ntv][0].i4 = *(const int4*)(P->vsbT + (ntv*16 + l15)*72 + quad*8);
            vb[ntv][1].i4 = *(const int4*)(P->vsbT + (ntv*16 + l15)*72 + 32 + quad*8);
        }
        #pragma unroll
        for (int mt = 0; mt < 2; ++mt) {
            FragU pa0, pa1;
            pa0.i4 = *(const int4*)(P->psb + (half*32 + mt*16 + l15)*72 + quad*8);
            pa1.i4 = *(const int4*)(P->psb + (half*32 + mt*16 + l15)*72 + 32 + quad*8);
            f32x4 ov0 = zf, ov1 = zf;
            ov0 = MFMA_B16(pa0.h8, vb[0][0].h8, ov0);
            ov0 = MFMA_B16(pa1.h8, vb[0][1].h8, ov0);
            ov1 = MFMA_B16(pa0.h8, vb[1][0].h8, ov1);
            ov1 = MFMA_B16(pa1.h8, vb[1][1].h8, ov1);
            #pragma unroll
            for (int rg = 0; rg < 4; ++rg) {
                P->oh[(rb + mt*16 + rg)*40 + l15]      = f2bf(ov0[rg]);
                P->oh[(rb + mt*16 + rg)*40 + 16 + l15] = f2bf(ov1[rg]);
            }
        }

        STOREW(3);
        __syncthreads();
        if (head < 5) LOADW(head + 1, 0);
        FragU ao0, ao1;
        ao0.i4 = *(const int4*)(P->oh + (half*32 + l15)*40 + quad*8);
        ao1.i4 = *(const int4*)(P->oh + (half*32 + 16 + l15)*40 + quad*8);
        #pragma unroll
        for (int nt = 0; nt < 12; ++nt) {
            FragU bp; bp.i4 = *(const int4*)(wbuf + (nt*16 + l15)*40 + quad*8);
            acc2[0][nt] = MFMA_B16(ao0.h8, bp.h8, acc2[0][nt]);
            acc2[1][nt] = MFMA_B16(ao1.h8, bp.h8, acc2[1][nt]);
        }
    }

    {
        float pb[12];
        #pragma unroll
        for (int nt = 0; nt < 12; ++nt) pb[nt] = projb[nt*16 + l15];
        #pragma unroll
        for (int mt = 0; mt < 2; ++mt) {
            #pragma unroll
            for (int rg = 0; rg < 4; ++rg) {
                const int tok = rb + mt*16 + rg;
                const int tr = tok >> 3, tc = tok & 7;
                const int ho2 = (hb * 8 + tr + 4) & 127;
                const int wo2 = (wb * 8 + tc + 4) & 127;
                const size_t base = ((size_t)b * L_TOK + ho2 * 128 + wo2) * C_DIM;
                #pragma unroll
                for (int nt = 0; nt < 12; ++nt) {
                    const int col = nt*16 + l15;
                    x1[base + col] = acc2[mt][nt][rg] + pb[nt] + x[base + col];
                }
            }
        }
    }
}

// ---------------------------------------------------------------------------
// Kernel 2 v8: WHOLE-TILE staging. Per hc: stage the full fc1 tile (96x192,
// padded stride 200) -> 72 MFMAs barrier-free; GELU (tanh-form, 1 exp);
// stage the full fc2 tile (192x96, stride 104) -> 72 MFMAs barrier-free.
// 4 barriers/hc (32 total vs 52). 9xint4 register prefetch (36 VGPR -- free,
// LDS-limited to 2 blocks/CU so VGPR<=256 costs nothing).
// LDS: wbig 39936 + union{xnA,hbuf} 26624 = 66560 -> 2 blocks/CU.
// ---------------------------------------------------------------------------
__global__ __launch_bounds__(256, 2) void k_mlp(
    const float* x1, const float* __restrict__ g2v, const float* __restrict__ b2v,
    const u16* __restrict__ fc1wT, const float* __restrict__ fc1b,
    const u16* __restrict__ fc2wT, const float* __restrict__ fc2b,
    float* out)
{
    union SmemU {
        u16 xnA[64 * 200];     // 25600 B  LN2'd tokens, one half at a time (prologue)
        u16 hbuf[128 * 104];   // 26624 B  GELU'd hidden chunk
    };
    __shared__ __align__(16) SmemU u;
    __shared__ __align__(16) u16 wbig[19968];  // 39936 B: fc1 [96][200] / fc2 [192][104]

    const int blk = blockIdx.x;
    const int t = threadIdx.x;
    const size_t row0 = (size_t)blk * 128;
    const int lane = t & 63, w = t >> 6;
    const int l15 = lane & 15, quad = lane >> 4;
    const f32x4 zf = {0.f, 0.f, 0.f, 0.f};

    // ---- prologue: LN2 + A-fragment pickup, one 64-token half at a time ----
    FragU afrag[2][6];
    for (int hf = 0; hf < 2; ++hf) {
        const int nn = t >> 2, q4 = t & 3;
        const int tok = hf * 64 + nn;
        const float* xp = x1 + (row0 + tok) * C_DIM + q4 * 48;
        float f[48];
        float sum = 0.f, sq = 0.f;
        #pragma unroll
        for (int i = 0; i < 12; ++i) {
            float4 v = *(const float4*)(xp + i * 4);
            f[i*4+0]=v.x; f[i*4+1]=v.y; f[i*4+2]=v.z; f[i*4+3]=v.w;
            sum += v.x+v.y+v.z+v.w;
            sq  += v.x*v.x + v.y*v.y + v.z*v.z + v.w*v.w;
        }
        sum += __shfl_xor(sum,1); sum += __shfl_xor(sum,2);
        sq  += __shfl_xor(sq,1);  sq  += __shfl_xor(sq,2);
        const float mu = sum * (1.f/192.f);
        const float rstd = rsqrtf(sq * (1.f/192.f) - mu*mu + 1e-5f);
        u16* xrow = u.xnA + nn * 200 + q4 * 48;
        #pragma unroll
        for (int i = 0; i < 6; ++i) {
            u32 pk[4];
            #pragma unroll
            for (int j = 0; j < 4; ++j) {
                float g0 = g2v[q4*48 + i*8 + j*2],     b0 = b2v[q4*48 + i*8 + j*2];
                float g1 = g2v[q4*48 + i*8 + j*2 + 1], b1 = b2v[q4*48 + i*8 + j*2 + 1];
                float y0 = (f[i*8+j*2]   - mu) * rstd * g0 + b0;
                float y1 = (f[i*8+j*2+1] - mu) * rstd * g1 + b1;
                pk[j] = (u32)f2bf(y0) | (((u32)f2bf(y1)) << 16);
            }
            *(int4*)(xrow + i*8) = make_int4((int)pk[0], (int)pk[1], (int)pk[2], (int)pk[3]);
        }
        __syncthreads();   // half staged
        #pragma unroll
        for (int kk = 0; kk < 6; ++kk)
            afrag[hf][kk].i4 = *(const int4*)(u.xnA + (w*16 + l15) * 200 + kk*32 + quad*8);
        __syncthreads();   // all reads done before xnA reuse / hbuf alias
    }

    // ---- whole-tile prefetch machinery: 9 int4/thread (2304 int4 = full tile)
    int4 wr[9];
    auto LOADW1 = [&](int hcL) {          // fc1 tile: 96 cols x 192 k
        #pragma unroll
        for (int i = 0; i < 9; ++i) {
            const int e = t + i * 256;
            const int cc = e / 24, seg = e % 24;
            wr[i] = *(const int4*)(fc1wT + (size_t)(hcL*96 + cc) * 192 + seg * 8);
        }
    };
    auto STORE1 = [&]() {                 // -> wbig [96][200]
        #pragma unroll
        for (int i = 0; i < 9; ++i) {
            const int e = t + i * 256;
            const int cc = e / 24, seg = e % 24;
            *(int4*)(wbig + cc * 200 + seg * 8) = wr[i];
        }
    };
    auto LOADW2 = [&](int hcL) {          // fc2 tile: 192 cols x 96 h
        #pragma unroll
        for (int i = 0; i < 9; ++i) {
            const int e = t + i * 256;
            const int c = e / 12, seg = e % 12;
            wr[i] = *(const int4*)(fc2wT + (size_t)c * 768 + hcL*96 + seg * 8);
        }
    };
    auto STORE2 = [&]() {                 // -> wbig [192][104]
        #pragma unroll
        for (int i = 0; i < 9; ++i) {
            const int e = t + i * 256;
            const int c = e / 12, seg = e % 12;
            *(int4*)(wbig + c * 104 + seg * 8) = wr[i];
        }
    };
    LOADW1(0);

    f32x4 acc2[2][12];
    #pragma unroll
    for (int mt = 0; mt < 2; ++mt)
        #pragma unroll
        for (int nt = 0; nt < 12; ++nt) acc2[mt][nt] = zf;

    for (int hc = 0; hc < 8; ++hc) {
        __syncthreads();          // A: all waves done reading wbig (prev fc2)
        STORE1();
        __syncthreads();          // B: fc1 tile visible
        f32x4 acc1[2][6];
        #pragma unroll
        for (int mt = 0; mt < 2; ++mt)
            #pragma unroll
            for (int nt = 0; nt < 6; ++nt) acc1[mt][nt] = zf;
        #pragma unroll
        for (int kc = 0; kc < 3; ++kc) {
            #pragma unroll
            for (int s = 0; s < 2; ++s) {
                FragU bf_[6];
                #pragma unroll
                for (int nt = 0; nt < 6; ++nt)
                    bf_[nt].i4 = *(const int4*)(wbig + (nt*16 + l15)*200 + kc*64 + s*32 + quad*8);
                #pragma unroll
                for (int nt = 0; nt < 6; ++nt) {
                    acc1[0][nt] = MFMA_B16(afrag[0][kc*2 + s].h8, bf_[nt].h8, acc1[0][nt]);
                    acc1[1][nt] = MFMA_B16(afrag[1][kc*2 + s].h8, bf_[nt].h8, acc1[1][nt]);
                }
            }
        }
        LOADW2(hc);               // prefetch fc2 tile; lands under GELU
        // ---- bias + tanh-form GELU -> hbuf (wave-private rows) ----
        #pragma unroll
        for (int nt = 0; nt < 6; ++nt) {
            const float bb = fc1b[hc*96 + nt*16 + l15];
            #pragma unroll
            for (int mt = 0; mt < 2; ++mt) {
                #pragma unroll
                for (int rg = 0; rg < 4; ++rg) {
                    float h = acc1[mt][nt][rg] + bb;
                    // gelu_tanh(h) = h * sigmoid(2*0.79788456*(h + 0.044715 h^3))
                    float e = __expf(h * (-1.5957691216057308f
                                          - 0.0713548162726302f * h * h));
                    float gl = h / (1.f + e);
                    u.hbuf[(mt*64 + w*16 + quad*4 + rg) * 104 + nt*16 + l15] = f2bf(gl);
                }
            }
        }
        __syncthreads();          // C: all waves done reading wbig (fc1)
        STORE2();
        __syncthreads();          // D: fc2 tile visible
        if (hc < 7) LOADW1(hc + 1);   // prefetch next fc1; lands under fc2 MFMAs
        #pragma unroll
        for (int sc = 0; sc < 3; ++sc) {
            FragU ha0, ha1;
            ha0.i4 = *(const int4*)(u.hbuf + (w*16 + l15) * 104 + sc*32 + quad*8);
            ha1.i4 = *(const int4*)(u.hbuf + (64 + w*16 + l15) * 104 + sc*32 + quad*8);
            FragU bf_[12];
            #pragma unroll
            for (int nt = 0; nt < 12; ++nt)
                bf_[nt].i4 = *(const int4*)(wbig + (nt*16 + l15)*104 + sc*32 + quad*8);
            #pragma unroll
            for (int nt = 0; nt < 12; ++nt) {
                acc2[0][nt] = MFMA_B16(ha0.h8, bf_[nt].h8, acc2[0][nt]);
                acc2[1][nt] = MFMA_B16(ha1.h8, bf_[nt].h8, acc2[1][nt]);
            }
        }
    }

    // ---- epilogue: + fc2 bias + residual (in-place safe: 1 owner per cell) ----
    #pragma unroll
    for (int nt = 0; nt < 12; ++nt) {
        const int col = nt*16 + l15;
        const float bb = fc2b[col];
        #pragma unroll
        for (int mt = 0; mt < 2; ++mt) {
            #pragma unroll
            for (int rg = 0; rg < 4; ++rg) {
                const size_t idx = (row0 + mt*64 + w*16 + quad*4 + rg) * C_DIM + col;
                out[idx] = acc2[mt][nt][rg] + bb + x1[idx];
            }
        }
    }
}

extern "C" void kernel_launch(void* const* d_in, const int* in_sizes, int n_in,
                              void* d_out, int out_size, void* d_ws, size_t ws_size,
                              hipStream_t stream) {
    const float* x     = (const float*)d_in[0];
    // d_in[1]=h, d_in[2]=w (ints, fixed 128 -> hardcoded)
    const float* g1v   = (const float*)d_in[3];
    const float* b1v   = (const float*)d_in[4];
    const float* qkvw  = (const float*)d_in[5];
    const float* qkvb  = (const float*)d_in[6];
    const float* projw = (const float*)d_in[7];
    const float* projb = (const float*)d_in[8];
    const float* relb  = (const float*)d_in[9];
    const float* g2v   = (const float*)d_in[10];
    const float* b2v   = (const float*)d_in[11];
    const float* fc1w  = (const float*)d_in[12];
    const float* fc1b  = (const float*)d_in[13];
    const float* fc2w  = (const float*)d_in[14];
    const float* fc2b  = (const float*)d_in[15];

    float* x1 = (float*)d_out;
    u16* wsb  = (u16*)d_ws;      // 884736 B of bf16 weights

    hipLaunchKernelGGL(k_cvt, dim3((CVT_TOT + 255) / 256), dim3(256), 0, stream,
                       qkvw, projw, fc1w, fc2w, wsb);
    hipLaunchKernelGGL(k_attnproj, dim3(1024), dim3(256), 0, stream,
                       x, g1v, b1v, wsb + OFF_QKV, qkvb, relb, wsb + OFF_PROJ, projb, x1);
    hipLaunchKernelGGL(k_mlp, dim3(1024), dim3(256), 0, stream,
                       x1, g2v, b2v, wsb + OFF_FC1, fc1b, wsb + OFF_FC2, fc2b, x1);
}

// Round 12
// 524.342 us; speedup vs baseline: 1.4063x; 1.4063x over previous
//
#include <hip/hip_runtime.h>

typedef unsigned short u16;
typedef unsigned int   u32;
typedef __attribute__((ext_vector_type(8))) short bf16x8;
typedef __attribute__((ext_vector_type(4))) float f32x4;

#define L_TOK   16384
#define C_DIM   192
#define HID_DIM 768

// bf16 weight workspace layout (u16 offsets)
#define OFF_QKV  0          // qkvwT[head][cc=grp*32+dim][k]   6*96*192   = 110592
#define OFF_PROJ 110592     // projT [head][c][j]              6*192*32   =  36864
#define OFF_FC1  147456     // fc1wT [h][k]                    768*192    = 147456
#define OFF_FC2  294912     // fc2wT [c][h]                    192*768    = 147456
#define CVT_TOT  442368     // total u16 elements (884736 B)

union FragU { int4 i4; bf16x8 h8; };

#define MFMA_B16(a,b,c) __builtin_amdgcn_mfma_f32_16x16x32_bf16(a,b,c,0,0,0)

__device__ __forceinline__ u16 f2bf(float f) {
    u32 t; __builtin_memcpy(&t, &f, 4);
    t += 0x7FFFu + ((t >> 16) & 1u);
    return (u16)(t >> 16);
}

// ---------------------------------------------------------------------------
// Kernel 0 v2: f32 -> bf16 weight convert+transpose, SOURCE-coalesced.
// ---------------------------------------------------------------------------
__global__ __launch_bounds__(256) void k_cvt(
    const float* __restrict__ qkvw, const float* __restrict__ projw,
    const float* __restrict__ fc1w, const float* __restrict__ fc2w,
    u16* __restrict__ ws)
{
    const int i = blockIdx.x * 256 + threadIdx.x;
    if (i >= CVT_TOT) return;
    float v; int dst;
    if (i < OFF_PROJ) {                      // qkvw[k][col], k=i/576
        const int k = i / 576, col = i % 576;
        const int grp = col / 192, rem = col % 192;
        const int head = rem >> 5, dim = rem & 31;
        v = qkvw[i];
        dst = OFF_QKV + head * (96 * 192) + (grp * 32 + dim) * 192 + k;
    } else if (i < OFF_FC1) {                // projw[cin][cout]
        const int s = i - OFF_PROJ;
        const int cin = s / 192, cout = s % 192;
        const int head = cin >> 5, j = cin & 31;
        v = projw[s];
        dst = OFF_PROJ + head * (192 * 32) + cout * 32 + j;
    } else if (i < OFF_FC2) {                // fc1w[k][h]
        const int s = i - OFF_FC1;
        const int k = s / 768, h = s % 768;
        v = fc1w[s];
        dst = OFF_FC1 + h * 192 + k;
    } else {                                 // fc2w[h][c]
        const int s = i - OFF_FC2;
        const int h = s / 192, c = s % 192;
        v = fc2w[s];
        dst = OFF_FC2 + c * 768 + h;
    }
    ws[dst] = f2bf(v);
}

// ---------------------------------------------------------------------------
// Kernel 1 v4 (R8, best-known): two windows per block + register-prefetched
// weight staging. LDS ~79.1KB -> 2 blocks/CU. UNCHANGED.
// ---------------------------------------------------------------------------
__global__ __launch_bounds__(256, 2) void k_attnproj(
    const float* __restrict__ x, const float* __restrict__ g1v, const float* __restrict__ b1v,
    const u16* __restrict__ qkvwT, const float* __restrict__ qkvb,
    const float* __restrict__ relb, const u16* __restrict__ projT, const float* __restrict__ projb,
    float* __restrict__ x1)
{
    struct PW {
        u16 qsb[64 * 40];
        u16 ksb[64 * 40];
        u16 vsbT[32 * 72];
        u16 psb[64 * 72];
        u16 oh [64 * 40];
    };                                      // 29184 B per window
    union SmemU {
        u16 xw[128 * 200];                  // 51200 B (phase A only, padded stride)
        PW pw[2];                           // 58368 B
    };
    __shared__ __align__(16) SmemU u;
    __shared__ __align__(16) u16 wbuf[192 * 40];   // 15360 B
    __shared__ float relbs[225 * 6];               //  5400 B

    const int t  = threadIdx.x;
    const int lane = t & 63, w = t >> 6;
    const int win = w >> 1, half = w & 1;
    const int l15 = lane & 15, quad = lane >> 4;
    const int wi2 = blockIdx.x * 2 + win;
    const int b  = wi2 >> 8;
    const int hb = (wi2 >> 4) & 15;
    const int wb = wi2 & 15;
    const bool maskon = (hb == 15) || (wb == 15);
    const f32x4 zf = {0.f, 0.f, 0.f, 0.f};

    for (int i = t; i < 225 * 6; i += 256) relbs[i] = relb[i];

    #pragma unroll
    for (int tk = 0; tk < 2; ++tk) {
        const int nn = t >> 2, q4 = t & 3;
        const int tok = tk * 64 + nn;
        const int tw = tok >> 6, n = tok & 63;
        const int wiA = blockIdx.x * 2 + tw;
        const int bA  = wiA >> 8;
        const int hbA = (wiA >> 4) & 15, wbA = wiA & 15;
        const int r = n >> 3, c = n & 7;
        const int ho = (hbA * 8 + r + 4) & 127;
        const int wo = (wbA * 8 + c + 4) & 127;
        const size_t xoff = ((size_t)bA * L_TOK + ho * 128 + wo) * C_DIM;
        const float* xp = x + xoff + q4 * 48;
        float f[48];
        float sum = 0.f, sq = 0.f;
        #pragma unroll
        for (int i = 0; i < 12; ++i) {
            float4 v = *(const float4*)(xp + i * 4);
            f[i*4+0]=v.x; f[i*4+1]=v.y; f[i*4+2]=v.z; f[i*4+3]=v.w;
            sum += v.x+v.y+v.z+v.w;
            sq  += v.x*v.x + v.y*v.y + v.z*v.z + v.w*v.w;
        }
        sum += __shfl_xor(sum, 1); sum += __shfl_xor(sum, 2);
        sq  += __shfl_xor(sq, 1);  sq  += __shfl_xor(sq, 2);
        const float mu = sum * (1.f / 192.f);
        const float rstd = rsqrtf(sq * (1.f / 192.f) - mu * mu + 1e-5f);
        u16* xrow = u.xw + tok * 200 + q4 * 48;
        #pragma unroll
        for (int i = 0; i < 6; ++i) {
            u32 pk[4];
            #pragma unroll
            for (int j = 0; j < 4; ++j) {
                float g0 = g1v[q4*48 + i*8 + j*2],     b0 = b1v[q4*48 + i*8 + j*2];
                float g1 = g1v[q4*48 + i*8 + j*2 + 1], b1 = b1v[q4*48 + i*8 + j*2 + 1];
                float y0 = (f[i*8+j*2]   - mu) * rstd * g0 + b0;
                float y1 = (f[i*8+j*2+1] - mu) * rstd * g1 + b1;
                pk[j] = (u32)f2bf(y0) | (((u32)f2bf(y1)) << 16);
            }
            *(int4*)(xrow + i * 8) = make_int4((int)pk[0], (int)pk[1], (int)pk[2], (int)pk[3]);
        }
    }
    __syncthreads();

    FragU afrag[2][6];
    #pragma unroll
    for (int mt = 0; mt < 2; ++mt)
        #pragma unroll
        for (int kk = 0; kk < 6; ++kk)
            afrag[mt][kk].i4 = *(const int4*)(u.xw +
                (win*64 + half*32 + mt*16 + l15) * 200 + kk*32 + quad*8);

    PW* P = &u.pw[win];
    const int rb = half*32 + quad*4;

    int4 wr0, wr1, wr2;
    auto LOADW = [&](int hh, int sub) {
        if (sub < 3) {
            const u16* src = qkvwT + (size_t)hh * (96 * 192) + sub * 64;
            wr0 = *(const int4*)(src + ((t      ) >> 3) * 192 + ((t      ) & 7) * 8);
            wr1 = *(const int4*)(src + ((t + 256) >> 3) * 192 + ((t + 256) & 7) * 8);
            wr2 = *(const int4*)(src + ((t + 512) >> 3) * 192 + ((t + 512) & 7) * 8);
        } else {
            const u16* src = projT + (size_t)hh * (192 * 32);
            wr0 = *(const int4*)(src + ((t      ) >> 2) * 32 + ((t      ) & 3) * 8);
            wr1 = *(const int4*)(src + ((t + 256) >> 2) * 32 + ((t + 256) & 3) * 8);
            wr2 = *(const int4*)(src + ((t + 512) >> 2) * 32 + ((t + 512) & 3) * 8);
        }
    };
    auto STOREW = [&](int sub) {
        if (sub < 3) {
            *(int4*)(wbuf + ((t      ) >> 3) * 72 + ((t      ) & 7) * 8) = wr0;
            *(int4*)(wbuf + ((t + 256) >> 3) * 72 + ((t + 256) & 7) * 8) = wr1;
            *(int4*)(wbuf + ((t + 512) >> 3) * 72 + ((t + 512) & 7) * 8) = wr2;
        } else {
            *(int4*)(wbuf + ((t      ) >> 2) * 40 + ((t      ) & 3) * 8) = wr0;
            *(int4*)(wbuf + ((t + 256) >> 2) * 40 + ((t + 256) & 3) * 8) = wr1;
            *(int4*)(wbuf + ((t + 512) >> 2) * 40 + ((t + 512) & 3) * 8) = wr2;
        }
    };
    LOADW(0, 0);

    f32x4 acc2[2][12];
    #pragma unroll
    for (int mt = 0; mt < 2; ++mt)
        #pragma unroll
        for (int nt = 0; nt < 12; ++nt) acc2[mt][nt] = zf;

    for (int head = 0; head < 6; ++head) {
        f32x4 accq[2][6];
        #pragma unroll
        for (int mt = 0; mt < 2; ++mt)
            #pragma unroll
            for (int nt = 0; nt < 6; ++nt) accq[mt][nt] = zf;

        for (int kc = 0; kc < 3; ++kc) {
            __syncthreads();
            STOREW(kc);
            __syncthreads();
            LOADW(head, kc + 1);
            #pragma unroll
            for (int s = 0; s < 2; ++s) {
                #pragma unroll
                for (int nt = 0; nt < 6; ++nt) {
                    FragU bf_;
                    bf_.i4 = *(const int4*)(wbuf + (nt*16 + l15)*72 + s*32 + quad*8);
                    accq[0][nt] = MFMA_B16(afrag[0][kc*2 + s].h8, bf_.h8, accq[0][nt]);
                    accq[1][nt] = MFMA_B16(afrag[1][kc*2 + s].h8, bf_.h8, accq[1][nt]);
                }
            }
        }
        #pragma unroll
        for (int mt = 0; mt < 2; ++mt) {
            #pragma unroll
            for (int nt = 0; nt < 6; ++nt) {
                const int grp = nt >> 1;
                const int dim = (nt & 1)*16 + l15;
                const float bias = qkvb[grp*192 + head*32 + dim];
                float vv[4];
                #pragma unroll
                for (int rg = 0; rg < 4; ++rg) vv[rg] = accq[mt][nt][rg] + bias;
                const int rowb = rb + mt*16;
                if (grp == 0) {
                    #pragma unroll
                    for (int rg = 0; rg < 4; ++rg)
                        P->qsb[(rowb + rg)*40 + dim] = f2bf(vv[rg] * 0.17677669529663687f);
                } else if (grp == 1) {
                    #pragma unroll
                    for (int rg = 0; rg < 4; ++rg)
                        P->ksb[(rowb + rg)*40 + dim] = f2bf(vv[rg]);
                } else {
                    u32 lo = (u32)f2bf(vv[0]) | (((u32)f2bf(vv[1])) << 16);
                    u32 hi = (u32)f2bf(vv[2]) | (((u32)f2bf(vv[3])) << 16);
                    *(uint2*)&P->vsbT[dim*72 + rowb] = make_uint2(lo, hi);
                }
            }
        }
        __syncthreads();

        FragU qf0, qf1;
        qf0.i4 = *(const int4*)(P->qsb + (half*32 + l15)*40 + quad*8);
        qf1.i4 = *(const int4*)(P->qsb + (half*32 + 16 + l15)*40 + quad*8);
        f32x4 sv[2][4];
        #pragma unroll
        for (int nt = 0; nt < 4; ++nt) {
            FragU kf; kf.i4 = *(const int4*)(P->ksb + (nt*16 + l15)*40 + quad*8);
            sv[0][nt] = MFMA_B16(qf0.h8, kf.h8, zf);
            sv[1][nt] = MFMA_B16(qf1.h8, kf.h8, zf);
        }
        const int kr_ = l15 >> 3, kc2 = l15 & 7;
        #pragma unroll
        for (int mt = 0; mt < 2; ++mt) {
            #pragma unroll
            for (int rg = 0; rg < 4; ++rg) {
                const int qm = rb + mt*16 + rg;
                const int qr = qm >> 3, qc = qm & 7;
                #pragma unroll
                for (int nt = 0; nt < 4; ++nt) {
                    const int kr = nt*2 + kr_;
                    sv[mt][nt][rg] += relbs[((qr - kr + 7)*15 + (qc - kc2 + 7))*6 + head];
                }
            }
        }
        if (maskon) {
            #pragma unroll
            for (int mt = 0; mt < 2; ++mt) {
                #pragma unroll
                for (int rg = 0; rg < 4; ++rg) {
                    const int qm = rb + mt*16 + rg;
                    const int qr = qm >> 3, qc = qm & 7;
                    const int regq = ((hb == 15) ? (qr < 4 ? 1 : 2) : 0) * 3
                                   + ((wb == 15) ? (qc < 4 ? 1 : 2) : 0);
                    #pragma unroll
                    for (int nt = 0; nt < 4; ++nt) {
                        const int kr = nt*2 + kr_;
                        const int regk = ((hb == 15) ? (kr < 4 ? 1 : 2) : 0) * 3
                                       + ((wb == 15) ? (kc2 < 4 ? 1 : 2) : 0);
                        if (regq != regk) sv[mt][nt][rg] -= 100.f;
                    }
                }
            }
        }
        #pragma unroll
        for (int mt = 0; mt < 2; ++mt) {
            #pragma unroll
            for (int rg = 0; rg < 4; ++rg) {
                float mx = fmaxf(fmaxf(sv[mt][0][rg], sv[mt][1][rg]),
                                 fmaxf(sv[mt][2][rg], sv[mt][3][rg]));
                mx = fmaxf(mx, __shfl_xor(mx, 1));
                mx = fmaxf(mx, __shfl_xor(mx, 2));
                mx = fmaxf(mx, __shfl_xor(mx, 4));
                mx = fmaxf(mx, __shfl_xor(mx, 8));
                float s0 = 0.f;
                #pragma unroll
                for (int nt = 0; nt < 4; ++nt) {
                    sv[mt][nt][rg] = __expf(sv[mt][nt][rg] - mx); s0 += sv[mt][nt][rg];
                }
                s0 += __shfl_xor(s0, 1); s0 += __shfl_xor(s0, 2);
                s0 += __shfl_xor(s0, 4); s0 += __shfl_xor(s0, 8);
                const float inv = 1.f / s0;
                #pragma unroll
                for (int nt = 0; nt < 4; ++nt)
                    P->psb[(rb + mt*16 + rg)*72 + nt*16 + l15] = f2bf(sv[mt][nt][rg] * inv);
            }
        }

        FragU vb[2][2];
        #pragma unroll
        for (int ntv = 0; ntv < 2; ++ntv) {
            vb[ntv][0].i4 = *(const int4*)(P->vsbT + (ntv*16 + l15)*72 + quad*8);
            vb[ntv][1].i4 = *(const int4*)(P->vsbT + (ntv*16 + l15)*72 + 32 + quad*8);
        }
        #pragma unroll
        for (int mt = 0; mt < 2; ++mt) {
            FragU pa0, pa1;
            pa0.i4 = *(const int4*)(P->psb + (half*32 + mt*16 + l15)*72 + quad*8);
            pa1.i4 = *(const int4*)(P->psb + (half*32 + mt*16 + l15)*72 + 32 + quad*8);
            f32x4 ov0 = zf, ov1 = zf;
            ov0 = MFMA_B16(pa0.h8, vb[0][0].h8, ov0);
            ov0 = MFMA_B16(pa1.h8, vb[0][1].h8, ov0);
            ov1 = MFMA_B16(pa0.h8, vb[1][0].h8, ov1);
            ov1 = MFMA_B16(pa1.h8, vb[1][1].h8, ov1);
            #pragma unroll
            for (int rg = 0; rg < 4; ++rg) {
                P->oh[(rb + mt*16 + rg)*40 + l15]      = f2bf(ov0[rg]);
                P->oh[(rb + mt*16 + rg)*40 + 16 + l15] = f2bf(ov1[rg]);
            }
        }

        STOREW(3);
        __syncthreads();
        if (head < 5) LOADW(head + 1, 0);
        FragU ao0, ao1;
        ao0.i4 = *(const int4*)(P->oh + (half*32 + l15)*40 + quad*8);
        ao1.i4 = *(const int4*)(P->oh + (half*32 + 16 + l15)*40 + quad*8);
        #pragma unroll
        for (int nt = 0; nt < 12; ++nt) {
            FragU bp; bp.i4 = *(const int4*)(wbuf + (nt*16 + l15)*40 + quad*8);
            acc2[0][nt] = MFMA_B16(ao0.h8, bp.h8, acc2[0][nt]);
            acc2[1][nt] = MFMA_B16(ao1.h8, bp.h8, acc2[1][nt]);
        }
    }

    {
        float pb[12];
        #pragma unroll
        for (int nt = 0; nt < 12; ++nt) pb[nt] = projb[nt*16 + l15];
        #pragma unroll
        for (int mt = 0; mt < 2; ++mt) {
            #pragma unroll
            for (int rg = 0; rg < 4; ++rg) {
                const int tok = rb + mt*16 + rg;
                const int tr = tok >> 3, tc = tok & 7;
                const int ho2 = (hb * 8 + tr + 4) & 127;
                const int wo2 = (wb * 8 + tc + 4) & 127;
                const size_t base = ((size_t)b * L_TOK + ho2 * 128 + wo2) * C_DIM;
                #pragma unroll
                for (int nt = 0; nt < 12; ++nt) {
                    const int col = nt*16 + l15;
                    x1[base + col] = acc2[mt][nt][rg] + pb[nt] + x[base + col];
                }
            }
        }
    }
}

// ---------------------------------------------------------------------------
// Kernel 2 v7b (R10 structure + tanh-GELU): double-buffered wT -> one barrier
// per stage (52 total); 3xint4 register prefetch (the largest that fits the
// ~200-VGPR live-state budget -- R11's 9xint4 spilled). GELU via 1 __expf.
// LDS 57.3KB, 2 blocks/CU, (256,2).
// ---------------------------------------------------------------------------
__global__ __launch_bounds__(256, 2) void k_mlp(
    const float* x1, const float* __restrict__ g2v, const float* __restrict__ b2v,
    const u16* __restrict__ fc1wT, const float* __restrict__ fc1b,
    const u16* __restrict__ fc2wT, const float* __restrict__ fc2b,
    float* out)
{
    union SmemU {
        u16 xnA[64 * 200];     // 25600 B  LN2'd tokens, one half at a time (prologue)
        u16 hbuf[128 * 104];   // 26624 B  GELU'd hidden chunk (xnA dead by then)
    };
    __shared__ __align__(16) SmemU u;
    __shared__ __align__(16) u16 wT[2][7680];   // 2 x 15360 B: w1T[96][72] / w2T[192][40]

    const int blk = blockIdx.x;
    const int t = threadIdx.x;
    const size_t row0 = (size_t)blk * 128;
    const int lane = t & 63, w = t >> 6;
    const int l15 = lane & 15, quad = lane >> 4;
    const f32x4 zf = {0.f, 0.f, 0.f, 0.f};

    // ---- prologue: LN2 + A-fragment pickup, one 64-token half at a time ----
    FragU afrag[2][6];
    for (int hf = 0; hf < 2; ++hf) {
        const int nn = t >> 2, q4 = t & 3;
        const int tok = hf * 64 + nn;
        const float* xp = x1 + (row0 + tok) * C_DIM + q4 * 48;
        float f[48];
        float sum = 0.f, sq = 0.f;
        #pragma unroll
        for (int i = 0; i < 12; ++i) {
            float4 v = *(const float4*)(xp + i * 4);
            f[i*4+0]=v.x; f[i*4+1]=v.y; f[i*4+2]=v.z; f[i*4+3]=v.w;
            sum += v.x+v.y+v.z+v.w;
            sq  += v.x*v.x + v.y*v.y + v.z*v.z + v.w*v.w;
        }
        sum += __shfl_xor(sum,1); sum += __shfl_xor(sum,2);
        sq  += __shfl_xor(sq,1);  sq  += __shfl_xor(sq,2);
        const float mu = sum * (1.f/192.f);
        const float rstd = rsqrtf(sq * (1.f/192.f) - mu*mu + 1e-5f);
        u16* xrow = u.xnA + nn * 200 + q4 * 48;
        #pragma unroll
        for (int i = 0; i < 6; ++i) {
            u32 pk[4];
            #pragma unroll
            for (int j = 0; j < 4; ++j) {
                float g0 = g2v[q4*48 + i*8 + j*2],     b0 = b2v[q4*48 + i*8 + j*2];
                float g1 = g2v[q4*48 + i*8 + j*2 + 1], b1 = b2v[q4*48 + i*8 + j*2 + 1];
                float y0 = (f[i*8+j*2]   - mu) * rstd * g0 + b0;
                float y1 = (f[i*8+j*2+1] - mu) * rstd * g1 + b1;
                pk[j] = (u32)f2bf(y0) | (((u32)f2bf(y1)) << 16);
            }
            *(int4*)(xrow + i*8) = make_int4((int)pk[0], (int)pk[1], (int)pk[2], (int)pk[3]);
        }
        __syncthreads();   // half staged
        #pragma unroll
        for (int kk = 0; kk < 6; ++kk)
            afrag[hf][kk].i4 = *(const int4*)(u.xnA + (w*16 + l15) * 200 + kk*32 + quad*8);
        __syncthreads();   // all reads done before xnA reuse / hbuf alias
    }

    // ---- weight prefetch machinery (stage sub: 0-2 fc1 kc, 3-5 fc2 sc) ----
    int4 wr0, wr1, wr2;
    auto LOADW = [&](int hcL, int sub) {
        if (sub < 3) {
            const u16* src = fc1wT + (size_t)(hcL * 96) * 192 + sub * 64;
            wr0 = *(const int4*)(src + ((t      ) >> 3) * 192 + ((t      ) & 7) * 8);
            wr1 = *(const int4*)(src + ((t + 256) >> 3) * 192 + ((t + 256) & 7) * 8);
            wr2 = *(const int4*)(src + ((t + 512) >> 3) * 192 + ((t + 512) & 7) * 8);
        } else {
            const u16* src = fc2wT + hcL * 96 + (sub - 3) * 32;
            wr0 = *(const int4*)(src + ((t      ) >> 2) * 768 + ((t      ) & 3) * 8);
            wr1 = *(const int4*)(src + ((t + 256) >> 2) * 768 + ((t + 256) & 3) * 8);
            wr2 = *(const int4*)(src + ((t + 512) >> 2) * 768 + ((t + 512) & 3) * 8);
        }
    };
    auto STOREW = [&](u16* dstb, int sub) {
        if (sub < 3) {
            *(int4*)(dstb + ((t      ) >> 3) * 72 + ((t      ) & 7) * 8) = wr0;
            *(int4*)(dstb + ((t + 256) >> 3) * 72 + ((t + 256) & 7) * 8) = wr1;
            *(int4*)(dstb + ((t + 512) >> 3) * 72 + ((t + 512) & 7) * 8) = wr2;
        } else {
            *(int4*)(dstb + ((t      ) >> 2) * 40 + ((t      ) & 3) * 8) = wr0;
            *(int4*)(dstb + ((t + 256) >> 2) * 40 + ((t + 256) & 3) * 8) = wr1;
            *(int4*)(dstb + ((t + 512) >> 2) * 40 + ((t + 512) & 3) * 8) = wr2;
        }
    };
    LOADW(0, 0);

    f32x4 acc2[2][12];
    #pragma unroll
    for (int mt = 0; mt < 2; ++mt)
        #pragma unroll
        for (int nt = 0; nt < 12; ++nt) acc2[mt][nt] = zf;

    int g = 0;   // global stage counter (buffer parity)
    for (int hc = 0; hc < 8; ++hc) {
        f32x4 acc1[2][6];
        #pragma unroll
        for (int mt = 0; mt < 2; ++mt)
            #pragma unroll
            for (int nt = 0; nt < 6; ++nt) acc1[mt][nt] = zf;

        for (int kc = 0; kc < 3; ++kc) {
            u16* buf = wT[g & 1];
            STOREW(buf, kc);       // overwrites stage g-2 (reads barrier-separated)
            __syncthreads();       // stage g visible
            LOADW(hc, kc + 1);     // prefetch next stage (kc+1 or fc2 sc0)
            #pragma unroll
            for (int s = 0; s < 2; ++s) {
                #pragma unroll
                for (int nt = 0; nt < 6; ++nt) {
                    FragU bf_;
                    bf_.i4 = *(const int4*)(buf + (nt*16 + l15)*72 + s*32 + quad*8);
                    acc1[0][nt] = MFMA_B16(afrag[0][kc*2 + s].h8, bf_.h8, acc1[0][nt]);
                    acc1[1][nt] = MFMA_B16(afrag[1][kc*2 + s].h8, bf_.h8, acc1[1][nt]);
                }
            }
            ++g;
        }
        // ---- bias + tanh-form GELU (1 exp) -> hbuf (wave-private rows) ----
        #pragma unroll
        for (int nt = 0; nt < 6; ++nt) {
            const float bb = fc1b[hc*96 + nt*16 + l15];
            #pragma unroll
            for (int mt = 0; mt < 2; ++mt) {
                #pragma unroll
                for (int rg = 0; rg < 4; ++rg) {
                    float h = acc1[mt][nt][rg] + bb;
                    // gelu_tanh(h) = h * sigmoid(1.5957691*h + 0.07135482*h^3)
                    float e = __expf(h * (-1.5957691216057308f
                                          - 0.0713548162726302f * h * h));
                    float gl = h / (1.f + e);
                    u.hbuf[(mt*64 + w*16 + quad*4 + rg) * 104 + nt*16 + l15] = f2bf(gl);
                }
            }
        }
        for (int sc = 0; sc < 3; ++sc) {
            u16* buf = wT[g & 1];
            STOREW(buf, 3 + sc);
            __syncthreads();
            if (sc < 2)           LOADW(hc, 4 + sc);
            else if (hc < 7)      LOADW(hc + 1, 0);
            FragU ha0, ha1;
            ha0.i4 = *(const int4*)(u.hbuf + (w*16 + l15) * 104 + sc*32 + quad*8);
            ha1.i4 = *(const int4*)(u.hbuf + (64 + w*16 + l15) * 104 + sc*32 + quad*8);
            #pragma unroll
            for (int nt = 0; nt < 12; ++nt) {
                FragU bf_;
                bf_.i4 = *(const int4*)(buf + (nt*16 + l15)*40 + quad*8);
                acc2[0][nt] = MFMA_B16(ha0.h8, bf_.h8, acc2[0][nt]);
                acc2[1][nt] = MFMA_B16(ha1.h8, bf_.h8, acc2[1][nt]);
            }
            ++g;
        }
    }

    // ---- epilogue: + fc2 bias + residual (in-place safe: 1 owner per cell) ----
    #pragma unroll
    for (int nt = 0; nt < 12; ++nt) {
        const int col = nt*16 + l15;
        const float bb = fc2b[col];
        #pragma unroll
        for (int mt = 0; mt < 2; ++mt) {
            #pragma unroll
            for (int rg = 0; rg < 4; ++rg) {
                const size_t idx = (row0 + mt*64 + w*16 + quad*4 + rg) * C_DIM + col;
                out[idx] = acc2[mt][nt][rg] + bb + x1[idx];
            }
        }
    }
}

extern "C" void kernel_launch(void* const* d_in, const int* in_sizes, int n_in,
                              void* d_out, int out_size, void* d_ws, size_t ws_size,
                              hipStream_t stream) {
    const float* x     = (const float*)d_in[0];
    // d_in[1]=h, d_in[2]=w (ints, fixed 128 -> hardcoded)
    const float* g1v   = (const float*)d_in[3];
    const float* b1v   = (const float*)d_in[4];
    const float* qkvw  = (const float*)d_in[5];
    const float* qkvb  = (const float*)d_in[6];
    const float* projw = (const float*)d_in[7];
    const float* projb = (const float*)d_in[8];
    const float* relb  = (const float*)d_in[9];
    const float* g2v   = (const float*)d_in[10];
    const float* b2v   = (const float*)d_in[11];
    const float* fc1w  = (const float*)d_in[12];
    const float* fc1b  = (const float*)d_in[13];
    const float* fc2w  = (const float*)d_in[14];
    const float* fc2b  = (const float*)d_in[15];

    float* x1 = (float*)d_out;
    u16* wsb  = (u16*)d_ws;      // 884736 B of bf16 weights

    hipLaunchKernelGGL(k_cvt, dim3((CVT_TOT + 255) / 256), dim3(256), 0, stream,
                       qkvw, projw, fc1w, fc2w, wsb);
    hipLaunchKernelGGL(k_attnproj, dim3(1024), dim3(256), 0, stream,
                       x, g1v, b1v, wsb + OFF_QKV, qkvb, relb, wsb + OFF_PROJ, projb, x1);
    hipLaunchKernelGGL(k_mlp, dim3(1024), dim3(256), 0, stream,
                       x1, g2v, b2v, wsb + OFF_FC1, fc1b, wsb + OFF_FC2, fc2b, x1);
}

// Round 13
// 513.605 us; speedup vs baseline: 1.4357x; 1.0209x over previous
//
#include <hip/hip_runtime.h>

typedef unsigned short u16;
typedef unsigned int   u32;
typedef __attribute__((ext_vector_type(8))) short bf16x8;
typedef __attribute__((ext_vector_type(4))) float f32x4;

#define L_TOK   16384
#define C_DIM   192
#define HID_DIM 768

// bf16 weight workspace layout (u16 offsets)
#define OFF_QKV  0          // qkvwT[head][cc=grp*32+dim][k]   6*96*192   = 110592
#define OFF_PROJ 110592     // projT [head][c][j]              6*192*32   =  36864
#define OFF_FC1  147456     // fc1 stage-tiles [hc*3+kc][6144] (swizzled)  = 147456
#define OFF_FC2  294912     // fc2 stage-tiles [hc*3+sc][6144] (swizzled)  = 147456
#define CVT_TOT  442368     // total u16 elements (884736 B)

union FragU { int4 i4; bf16x8 h8; };

#define MFMA_B16(a,b,c) __builtin_amdgcn_mfma_f32_16x16x32_bf16(a,b,c,0,0,0)

__device__ __forceinline__ u16 f2bf(float f) {
    u32 t; __builtin_memcpy(&t, &f, 4);
    t += 0x7FFFu + ((t >> 16) & 1u);
    return (u16)(t >> 16);
}

// ---------------------------------------------------------------------------
// Kernel 0 v3: f32 -> bf16 weight convert+transpose, SOURCE-coalesced.
// fc1/fc2 are written as per-stage 12KB tiles with the LDS bank-swizzle
// BAKED INTO the layout (m173 pattern): k_mlp stages them with linear
// global_load_lds and reads fragments with the matching XOR'd address.
//   fc1 tile (hc,kc): q = cc*64 + (ko ^ ((cc&7)<<3)),  cc=h%96, ko=k%64
//   fc2 tile (hc,sc): q = c*32  + (ho ^ ((c&3)<<3)),   ho = h%32
// ---------------------------------------------------------------------------
__global__ __launch_bounds__(256) void k_cvt(
    const float* __restrict__ qkvw, const float* __restrict__ projw,
    const float* __restrict__ fc1w, const float* __restrict__ fc2w,
    u16* __restrict__ ws)
{
    const int i = blockIdx.x * 256 + threadIdx.x;
    if (i >= CVT_TOT) return;
    float v; int dst;
    if (i < OFF_PROJ) {                      // qkvw[k][col], k=i/576
        const int k = i / 576, col = i % 576;
        const int grp = col / 192, rem = col % 192;
        const int head = rem >> 5, dim = rem & 31;
        v = qkvw[i];
        dst = OFF_QKV + head * (96 * 192) + (grp * 32 + dim) * 192 + k;
    } else if (i < OFF_FC1) {                // projw[cin][cout]
        const int s = i - OFF_PROJ;
        const int cin = s / 192, cout = s % 192;
        const int head = cin >> 5, j = cin & 31;
        v = projw[s];
        dst = OFF_PROJ + head * (192 * 32) + cout * 32 + j;
    } else if (i < OFF_FC2) {                // fc1w[k][h] -> swizzled stage tiles
        const int s = i - OFF_FC1;
        const int k = s / 768, h = s % 768;
        v = fc1w[s];
        const int hc = h / 96, cc = h % 96;
        const int kc = k >> 6, ko = k & 63;
        const int q = cc * 64 + (ko ^ ((cc & 7) << 3));
        dst = OFF_FC1 + (hc * 3 + kc) * 6144 + q;
    } else {                                 // fc2w[h][c] -> swizzled stage tiles
        const int s = i - OFF_FC2;
        const int h = s / 192, c = s % 192;
        v = fc2w[s];
        const int hc = h / 96, rem = h % 96;
        const int sc = rem >> 5, ho = rem & 31;
        const int q = c * 32 + (ho ^ ((c & 3) << 3));
        dst = OFF_FC2 + (hc * 3 + sc) * 6144 + q;
    }
    ws[dst] = f2bf(v);
}

// ---------------------------------------------------------------------------
// Kernel 1 v4 (R8/R12, best-known): two windows per block + register-
// prefetched weight staging. LDS ~79.1KB. UNCHANGED.
// ---------------------------------------------------------------------------
__global__ __launch_bounds__(256, 2) void k_attnproj(
    const float* __restrict__ x, const float* __restrict__ g1v, const float* __restrict__ b1v,
    const u16* __restrict__ qkvwT, const float* __restrict__ qkvb,
    const float* __restrict__ relb, const u16* __restrict__ projT, const float* __restrict__ projb,
    float* __restrict__ x1)
{
    struct PW {
        u16 qsb[64 * 40];
        u16 ksb[64 * 40];
        u16 vsbT[32 * 72];
        u16 psb[64 * 72];
        u16 oh [64 * 40];
    };                                      // 29184 B per window
    union SmemU {
        u16 xw[128 * 200];                  // 51200 B (phase A only, padded stride)
        PW pw[2];                           // 58368 B
    };
    __shared__ __align__(16) SmemU u;
    __shared__ __align__(16) u16 wbuf[192 * 40];   // 15360 B
    __shared__ float relbs[225 * 6];               //  5400 B

    const int t  = threadIdx.x;
    const int lane = t & 63, w = t >> 6;
    const int win = w >> 1, half = w & 1;
    const int l15 = lane & 15, quad = lane >> 4;
    const int wi2 = blockIdx.x * 2 + win;
    const int b  = wi2 >> 8;
    const int hb = (wi2 >> 4) & 15;
    const int wb = wi2 & 15;
    const bool maskon = (hb == 15) || (wb == 15);
    const f32x4 zf = {0.f, 0.f, 0.f, 0.f};

    for (int i = t; i < 225 * 6; i += 256) relbs[i] = relb[i];

    #pragma unroll
    for (int tk = 0; tk < 2; ++tk) {
        const int nn = t >> 2, q4 = t & 3;
        const int tok = tk * 64 + nn;
        const int tw = tok >> 6, n = tok & 63;
        const int wiA = blockIdx.x * 2 + tw;
        const int bA  = wiA >> 8;
        const int hbA = (wiA >> 4) & 15, wbA = wiA & 15;
        const int r = n >> 3, c = n & 7;
        const int ho = (hbA * 8 + r + 4) & 127;
        const int wo = (wbA * 8 + c + 4) & 127;
        const size_t xoff = ((size_t)bA * L_TOK + ho * 128 + wo) * C_DIM;
        const float* xp = x + xoff + q4 * 48;
        float f[48];
        float sum = 0.f, sq = 0.f;
        #pragma unroll
        for (int i = 0; i < 12; ++i) {
            float4 v = *(const float4*)(xp + i * 4);
            f[i*4+0]=v.x; f[i*4+1]=v.y; f[i*4+2]=v.z; f[i*4+3]=v.w;
            sum += v.x+v.y+v.z+v.w;
            sq  += v.x*v.x + v.y*v.y + v.z*v.z + v.w*v.w;
        }
        sum += __shfl_xor(sum, 1); sum += __shfl_xor(sum, 2);
        sq  += __shfl_xor(sq, 1);  sq  += __shfl_xor(sq, 2);
        const float mu = sum * (1.f / 192.f);
        const float rstd = rsqrtf(sq * (1.f / 192.f) - mu * mu + 1e-5f);
        u16* xrow = u.xw + tok * 200 + q4 * 48;
        #pragma unroll
        for (int i = 0; i < 6; ++i) {
            u32 pk[4];
            #pragma unroll
            for (int j = 0; j < 4; ++j) {
                float g0 = g1v[q4*48 + i*8 + j*2],     b0 = b1v[q4*48 + i*8 + j*2];
                float g1 = g1v[q4*48 + i*8 + j*2 + 1], b1 = b1v[q4*48 + i*8 + j*2 + 1];
                float y0 = (f[i*8+j*2]   - mu) * rstd * g0 + b0;
                float y1 = (f[i*8+j*2+1] - mu) * rstd * g1 + b1;
                pk[j] = (u32)f2bf(y0) | (((u32)f2bf(y1)) << 16);
            }
            *(int4*)(xrow + i * 8) = make_int4((int)pk[0], (int)pk[1], (int)pk[2], (int)pk[3]);
        }
    }
    __syncthreads();

    FragU afrag[2][6];
    #pragma unroll
    for (int mt = 0; mt < 2; ++mt)
        #pragma unroll
        for (int kk = 0; kk < 6; ++kk)
            afrag[mt][kk].i4 = *(const int4*)(u.xw +
                (win*64 + half*32 + mt*16 + l15) * 200 + kk*32 + quad*8);

    PW* P = &u.pw[win];
    const int rb = half*32 + quad*4;

    int4 wr0, wr1, wr2;
    auto LOADW = [&](int hh, int sub) {
        if (sub < 3) {
            const u16* src = qkvwT + (size_t)hh * (96 * 192) + sub * 64;
            wr0 = *(const int4*)(src + ((t      ) >> 3) * 192 + ((t      ) & 7) * 8);
            wr1 = *(const int4*)(src + ((t + 256) >> 3) * 192 + ((t + 256) & 7) * 8);
            wr2 = *(const int4*)(src + ((t + 512) >> 3) * 192 + ((t + 512) & 7) * 8);
        } else {
            const u16* src = projT + (size_t)hh * (192 * 32);
            wr0 = *(const int4*)(src + ((t      ) >> 2) * 32 + ((t      ) & 3) * 8);
            wr1 = *(const int4*)(src + ((t + 256) >> 2) * 32 + ((t + 256) & 3) * 8);
            wr2 = *(const int4*)(src + ((t + 512) >> 2) * 32 + ((t + 512) & 3) * 8);
        }
    };
    auto STOREW = [&](int sub) {
        if (sub < 3) {
            *(int4*)(wbuf + ((t      ) >> 3) * 72 + ((t      ) & 7) * 8) = wr0;
            *(int4*)(wbuf + ((t + 256) >> 3) * 72 + ((t + 256) & 7) * 8) = wr1;
            *(int4*)(wbuf + ((t + 512) >> 3) * 72 + ((t + 512) & 7) * 8) = wr2;
        } else {
            *(int4*)(wbuf + ((t      ) >> 2) * 40 + ((t      ) & 3) * 8) = wr0;
            *(int4*)(wbuf + ((t + 256) >> 2) * 40 + ((t + 256) & 3) * 8) = wr1;
            *(int4*)(wbuf + ((t + 512) >> 2) * 40 + ((t + 512) & 3) * 8) = wr2;
        }
    };
    LOADW(0, 0);

    f32x4 acc2[2][12];
    #pragma unroll
    for (int mt = 0; mt < 2; ++mt)
        #pragma unroll
        for (int nt = 0; nt < 12; ++nt) acc2[mt][nt] = zf;

    for (int head = 0; head < 6; ++head) {
        f32x4 accq[2][6];
        #pragma unroll
        for (int mt = 0; mt < 2; ++mt)
            #pragma unroll
            for (int nt = 0; nt < 6; ++nt) accq[mt][nt] = zf;

        for (int kc = 0; kc < 3; ++kc) {
            __syncthreads();
            STOREW(kc);
            __syncthreads();
            LOADW(head, kc + 1);
            #pragma unroll
            for (int s = 0; s < 2; ++s) {
                #pragma unroll
                for (int nt = 0; nt < 6; ++nt) {
                    FragU bf_;
                    bf_.i4 = *(const int4*)(wbuf + (nt*16 + l15)*72 + s*32 + quad*8);
                    accq[0][nt] = MFMA_B16(afrag[0][kc*2 + s].h8, bf_.h8, accq[0][nt]);
                    accq[1][nt] = MFMA_B16(afrag[1][kc*2 + s].h8, bf_.h8, accq[1][nt]);
                }
            }
        }
        #pragma unroll
        for (int mt = 0; mt < 2; ++mt) {
            #pragma unroll
            for (int nt = 0; nt < 6; ++nt) {
                const int grp = nt >> 1;
                const int dim = (nt & 1)*16 + l15;
                const float bias = qkvb[grp*192 + head*32 + dim];
                float vv[4];
                #pragma unroll
                for (int rg = 0; rg < 4; ++rg) vv[rg] = accq[mt][nt][rg] + bias;
                const int rowb = rb + mt*16;
                if (grp == 0) {
                    #pragma unroll
                    for (int rg = 0; rg < 4; ++rg)
                        P->qsb[(rowb + rg)*40 + dim] = f2bf(vv[rg] * 0.17677669529663687f);
                } else if (grp == 1) {
                    #pragma unroll
                    for (int rg = 0; rg < 4; ++rg)
                        P->ksb[(rowb + rg)*40 + dim] = f2bf(vv[rg]);
                } else {
                    u32 lo = (u32)f2bf(vv[0]) | (((u32)f2bf(vv[1])) << 16);
                    u32 hi = (u32)f2bf(vv[2]) | (((u32)f2bf(vv[3])) << 16);
                    *(uint2*)&P->vsbT[dim*72 + rowb] = make_uint2(lo, hi);
                }
            }
        }
        __syncthreads();

        FragU qf0, qf1;
        qf0.i4 = *(const int4*)(P->qsb + (half*32 + l15)*40 + quad*8);
        qf1.i4 = *(const int4*)(P->qsb + (half*32 + 16 + l15)*40 + quad*8);
        f32x4 sv[2][4];
        #pragma unroll
        for (int nt = 0; nt < 4; ++nt) {
            FragU kf; kf.i4 = *(const int4*)(P->ksb + (nt*16 + l15)*40 + quad*8);
            sv[0][nt] = MFMA_B16(qf0.h8, kf.h8, zf);
            sv[1][nt] = MFMA_B16(qf1.h8, kf.h8, zf);
        }
        const int kr_ = l15 >> 3, kc2 = l15 & 7;
        #pragma unroll
        for (int mt = 0; mt < 2; ++mt) {
            #pragma unroll
            for (int rg = 0; rg < 4; ++rg) {
                const int qm = rb + mt*16 + rg;
                const int qr = qm >> 3, qc = qm & 7;
                #pragma unroll
                for (int nt = 0; nt < 4; ++nt) {
                    const int kr = nt*2 + kr_;
                    sv[mt][nt][rg] += relbs[((qr - kr + 7)*15 + (qc - kc2 + 7))*6 + head];
                }
            }
        }
        if (maskon) {
            #pragma unroll
            for (int mt = 0; mt < 2; ++mt) {
                #pragma unroll
                for (int rg = 0; rg < 4; ++rg) {
                    const int qm = rb + mt*16 + rg;
                    const int qr = qm >> 3, qc = qm & 7;
                    const int regq = ((hb == 15) ? (qr < 4 ? 1 : 2) : 0) * 3
                                   + ((wb == 15) ? (qc < 4 ? 1 : 2) : 0);
                    #pragma unroll
                    for (int nt = 0; nt < 4; ++nt) {
                        const int kr = nt*2 + kr_;
                        const int regk = ((hb == 15) ? (kr < 4 ? 1 : 2) : 0) * 3
                                       + ((wb == 15) ? (kc2 < 4 ? 1 : 2) : 0);
                        if (regq != regk) sv[mt][nt][rg] -= 100.f;
                    }
                }
            }
        }
        #pragma unroll
        for (int mt = 0; mt < 2; ++mt) {
            #pragma unroll
            for (int rg = 0; rg < 4; ++rg) {
                float mx = fmaxf(fmaxf(sv[mt][0][rg], sv[mt][1][rg]),
                                 fmaxf(sv[mt][2][rg], sv[mt][3][rg]));
                mx = fmaxf(mx, __shfl_xor(mx, 1));
                mx = fmaxf(mx, __shfl_xor(mx, 2));
                mx = fmaxf(mx, __shfl_xor(mx, 4));
                mx = fmaxf(mx, __shfl_xor(mx, 8));
                float s0 = 0.f;
                #pragma unroll
                for (int nt = 0; nt < 4; ++nt) {
                    sv[mt][nt][rg] = __expf(sv[mt][nt][rg] - mx); s0 += sv[mt][nt][rg];
                }
                s0 += __shfl_xor(s0, 1); s0 += __shfl_xor(s0, 2);
                s0 += __shfl_xor(s0, 4); s0 += __shfl_xor(s0, 8);
                const float inv = 1.f / s0;
                #pragma unroll
                for (int nt = 0; nt < 4; ++nt)
                    P->psb[(rb + mt*16 + rg)*72 + nt*16 + l15] = f2bf(sv[mt][nt][rg] * inv);
            }
        }

        FragU vb[2][2];
        #pragma unroll
        for (int ntv = 0; ntv < 2; ++ntv) {
            vb[ntv][0].i4 = *(const int4*)(P->vsbT + (ntv*16 + l15)*72 + quad*8);
            vb[ntv][1].i4 = *(const int4*)(P->vsbT + (ntv*16 + l15)*72 + 32 + quad*8);
        }
        #pragma unroll
        for (int mt = 0; mt < 2; ++mt) {
            FragU pa0, pa1;
            pa0.i4 = *(const int4*)(P->psb + (half*32 + mt*16 + l15)*72 + quad*8);
            pa1.i4 = *(const int4*)(P->psb + (half*32 + mt*16 + l15)*72 + 32 + quad*8);
            f32x4 ov0 = zf, ov1 = zf;
            ov0 = MFMA_B16(pa0.h8, vb[0][0].h8, ov0);
            ov0 = MFMA_B16(pa1.h8, vb[0][1].h8, ov0);
            ov1 = MFMA_B16(pa0.h8, vb[1][0].h8, ov1);
            ov1 = MFMA_B16(pa1.h8, vb[1][1].h8, ov1);
            #pragma unroll
            for (int rg = 0; rg < 4; ++rg) {
                P->oh[(rb + mt*16 + rg)*40 + l15]      = f2bf(ov0[rg]);
                P->oh[(rb + mt*16 + rg)*40 + 16 + l15] = f2bf(ov1[rg]);
            }
        }

        STOREW(3);
        __syncthreads();
        if (head < 5) LOADW(head + 1, 0);
        FragU ao0, ao1;
        ao0.i4 = *(const int4*)(P->oh + (half*32 + l15)*40 + quad*8);
        ao1.i4 = *(const int4*)(P->oh + (half*32 + 16 + l15)*40 + quad*8);
        #pragma unroll
        for (int nt = 0; nt < 12; ++nt) {
            FragU bp; bp.i4 = *(const int4*)(wbuf + (nt*16 + l15)*40 + quad*8);
            acc2[0][nt] = MFMA_B16(ao0.h8, bp.h8, acc2[0][nt]);
            acc2[1][nt] = MFMA_B16(ao1.h8, bp.h8, acc2[1][nt]);
        }
    }

    {
        float pb[12];
        #pragma unroll
        for (int nt = 0; nt < 12; ++nt) pb[nt] = projb[nt*16 + l15];
        #pragma unroll
        for (int mt = 0; mt < 2; ++mt) {
            #pragma unroll
            for (int rg = 0; rg < 4; ++rg) {
                const int tok = rb + mt*16 + rg;
                const int tr = tok >> 3, tc = tok & 7;
                const int ho2 = (hb * 8 + tr + 4) & 127;
                const int wo2 = (wb * 8 + tc + 4) & 127;
                const size_t base = ((size_t)b * L_TOK + ho2 * 128 + wo2) * C_DIM;
                #pragma unroll
                for (int nt = 0; nt < 12; ++nt) {
                    const int col = nt*16 + l15;
                    x1[base + col] = acc2[mt][nt][rg] + pb[nt] + x[base + col];
                }
            }
        }
    }
}

// ---------------------------------------------------------------------------
// Kernel 2 v10: async-staged weights via global_load_lds. Per 12KB stage
// tile: ONE barrier -> issue 12x1KB gll for stage g+1 (no registers, no
// ds_write, no addressing VALU) -> swizzled ds_read + MFMA on stage g.
// Bank-conflict-free via swizzle baked into ws by k_cvt (m173/T2 pattern).
// LDS: wbig[2][12288B] + union{xnA,hbuf} 26624 = 51200 B.
// ---------------------------------------------------------------------------
__global__ __launch_bounds__(256, 2) void k_mlp(
    const float* x1, const float* __restrict__ g2v, const float* __restrict__ b2v,
    const u16* __restrict__ fc1wT, const float* __restrict__ fc1b,
    const u16* __restrict__ fc2wT, const float* __restrict__ fc2b,
    float* out)
{
    union SmemU {
        u16 xnA[64 * 200];     // 25600 B  LN2'd tokens, one half at a time (prologue)
        u16 hbuf[128 * 104];   // 26624 B  GELU'd hidden chunk (xnA dead by then)
    };
    __shared__ __align__(16) SmemU u;
    __shared__ __align__(16) u16 wbig[2][6144];   // 2 x 12288 B stage tiles

    const int blk = blockIdx.x;
    const int t = threadIdx.x;
    const size_t row0 = (size_t)blk * 128;
    const int lane = t & 63, w = t >> 6;
    const int l15 = lane & 15, quad = lane >> 4;
    const f32x4 zf = {0.f, 0.f, 0.f, 0.f};

    // ---- async stage-tile issue: stage st -> wbig[st&1], 3 gll per wave ----
    auto issue_stage = [&](int st) {
        const int hcs = st / 6, sub = st % 6;
        const u16* src = (sub < 3) ? fc1wT + (hcs * 3 + sub) * 6144
                                   : fc2wT + (hcs * 3 + (sub - 3)) * 6144;
        u16* dstb = &wbig[st & 1][0];
        #pragma unroll
        for (int c = 0; c < 3; ++c) {
            const int cid = c * 4 + w;            // 12 x 512-u16 chunks
            __builtin_amdgcn_global_load_lds(
                (const __attribute__((address_space(1))) void*)(src + cid * 512 + lane * 8),
                (__attribute__((address_space(3))) void*)(dstb + cid * 512),
                16, 0, 0);
        }
    };
    issue_stage(0);   // in flight under the LN prologue

    // ---- prologue: LN2 + A-fragment pickup, one 64-token half at a time ----
    FragU afrag[2][6];
    for (int hf = 0; hf < 2; ++hf) {
        const int nn = t >> 2, q4 = t & 3;
        const int tok = hf * 64 + nn;
        const float* xp = x1 + (row0 + tok) * C_DIM + q4 * 48;
        float f[48];
        float sum = 0.f, sq = 0.f;
        #pragma unroll
        for (int i = 0; i < 12; ++i) {
            float4 v = *(const float4*)(xp + i * 4);
            f[i*4+0]=v.x; f[i*4+1]=v.y; f[i*4+2]=v.z; f[i*4+3]=v.w;
            sum += v.x+v.y+v.z+v.w;
            sq  += v.x*v.x + v.y*v.y + v.z*v.z + v.w*v.w;
        }
        sum += __shfl_xor(sum,1); sum += __shfl_xor(sum,2);
        sq  += __shfl_xor(sq,1);  sq  += __shfl_xor(sq,2);
        const float mu = sum * (1.f/192.f);
        const float rstd = rsqrtf(sq * (1.f/192.f) - mu*mu + 1e-5f);
        u16* xrow = u.xnA + nn * 200 + q4 * 48;
        #pragma unroll
        for (int i = 0; i < 6; ++i) {
            u32 pk[4];
            #pragma unroll
            for (int j = 0; j < 4; ++j) {
                float g0 = g2v[q4*48 + i*8 + j*2],     b0 = b2v[q4*48 + i*8 + j*2];
                float g1 = g2v[q4*48 + i*8 + j*2 + 1], b1 = b2v[q4*48 + i*8 + j*2 + 1];
                float y0 = (f[i*8+j*2]   - mu) * rstd * g0 + b0;
                float y1 = (f[i*8+j*2+1] - mu) * rstd * g1 + b1;
                pk[j] = (u32)f2bf(y0) | (((u32)f2bf(y1)) << 16);
            }
            *(int4*)(xrow + i*8) = make_int4((int)pk[0], (int)pk[1], (int)pk[2], (int)pk[3]);
        }
        __syncthreads();   // half staged
        #pragma unroll
        for (int kk = 0; kk < 6; ++kk)
            afrag[hf][kk].i4 = *(const int4*)(u.xnA + (w*16 + l15) * 200 + kk*32 + quad*8);
        __syncthreads();   // all reads done before xnA reuse / hbuf alias
    }

    f32x4 acc2[2][12];
    #pragma unroll
    for (int mt = 0; mt < 2; ++mt)
        #pragma unroll
        for (int nt = 0; nt < 12; ++nt) acc2[mt][nt] = zf;

    int g = 0;   // stage counter; stage g lives in wbig[g&1]
    for (int hc = 0; hc < 8; ++hc) {
        f32x4 acc1[2][6];
        #pragma unroll
        for (int mt = 0; mt < 2; ++mt)
            #pragma unroll
            for (int nt = 0; nt < 6; ++nt) acc1[mt][nt] = zf;

        // ---- fc1: 3 stage tiles [96 cols][64 k], swz ^((row&7)<<3) ----
        for (int kc = 0; kc < 3; ++kc) {
            __syncthreads();            // stage g ready (vmcnt drained); g-1 readers done
            if (g < 47) issue_stage(g + 1);
            const u16* buf = &wbig[g & 1][0];
            #pragma unroll
            for (int s = 0; s < 2; ++s) {
                #pragma unroll
                for (int nt = 0; nt < 6; ++nt) {
                    const int row = nt*16 + l15;
                    FragU bf_;
                    bf_.i4 = *(const int4*)(buf + row*64 +
                                            ((s*32 + quad*8) ^ ((row & 7) << 3)));
                    acc1[0][nt] = MFMA_B16(afrag[0][kc*2 + s].h8, bf_.h8, acc1[0][nt]);
                    acc1[1][nt] = MFMA_B16(afrag[1][kc*2 + s].h8, bf_.h8, acc1[1][nt]);
                }
            }
            ++g;
        }
        // ---- bias + tanh-form GELU (1 exp) -> hbuf (wave-private rows) ----
        #pragma unroll
        for (int nt = 0; nt < 6; ++nt) {
            const float bb = fc1b[hc*96 + nt*16 + l15];
            #pragma unroll
            for (int mt = 0; mt < 2; ++mt) {
                #pragma unroll
                for (int rg = 0; rg < 4; ++rg) {
                    float h = acc1[mt][nt][rg] + bb;
                    float e = __expf(h * (-1.5957691216057308f
                                          - 0.0713548162726302f * h * h));
                    float gl = h / (1.f + e);
                    u.hbuf[(mt*64 + w*16 + quad*4 + rg) * 104 + nt*16 + l15] = f2bf(gl);
                }
            }
        }
        // ---- fc2: 3 stage tiles [192 cols][32 h], swz ^((row&3)<<3) ----
        for (int sc = 0; sc < 3; ++sc) {
            __syncthreads();
            if (g < 47) issue_stage(g + 1);
            const u16* buf = &wbig[g & 1][0];
            FragU ha0, ha1;
            ha0.i4 = *(const int4*)(u.hbuf + (w*16 + l15) * 104 + sc*32 + quad*8);
            ha1.i4 = *(const int4*)(u.hbuf + (64 + w*16 + l15) * 104 + sc*32 + quad*8);
            #pragma unroll
            for (int nt = 0; nt < 12; ++nt) {
                const int row = nt*16 + l15;
                FragU bf_;
                bf_.i4 = *(const int4*)(buf + row*32 +
                                        ((quad*8) ^ ((row & 3) << 3)));
                acc2[0][nt] = MFMA_B16(ha0.h8, bf_.h8, acc2[0][nt]);
                acc2[1][nt] = MFMA_B16(ha1.h8, bf_.h8, acc2[1][nt]);
            }
            ++g;
        }
    }

    // ---- epilogue: + fc2 bias + residual (in-place safe: 1 owner per cell) ----
    #pragma unroll
    for (int nt = 0; nt < 12; ++nt) {
        const int col = nt*16 + l15;
        const float bb = fc2b[col];
        #pragma unroll
        for (int mt = 0; mt < 2; ++mt) {
            #pragma unroll
            for (int rg = 0; rg < 4; ++rg) {
                const size_t idx = (row0 + mt*64 + w*16 + quad*4 + rg) * C_DIM + col;
                out[idx] = acc2[mt][nt][rg] + bb + x1[idx];
            }
        }
    }
}

extern "C" void kernel_launch(void* const* d_in, const int* in_sizes, int n_in,
                              void* d_out, int out_size, void* d_ws, size_t ws_size,
                              hipStream_t stream) {
    const float* x     = (const float*)d_in[0];
    // d_in[1]=h, d_in[2]=w (ints, fixed 128 -> hardcoded)
    const float* g1v   = (const float*)d_in[3];
    const float* b1v   = (const float*)d_in[4];
    const float* qkvw  = (const float*)d_in[5];
    const float* qkvb  = (const float*)d_in[6];
    const float* projw = (const float*)d_in[7];
    const float* projb = (const float*)d_in[8];
    const float* relb  = (const float*)d_in[9];
    const float* g2v   = (const float*)d_in[10];
    const float* b2v   = (const float*)d_in[11];
    const float* fc1w  = (const float*)d_in[12];
    const float* fc1b  = (const float*)d_in[13];
    const float* fc2w  = (const float*)d_in[14];
    const float* fc2b  = (const float*)d_in[15];

    float* x1 = (float*)d_out;
    u16* wsb  = (u16*)d_ws;      // 884736 B of bf16 weights

    hipLaunchKernelGGL(k_cvt, dim3((CVT_TOT + 255) / 256), dim3(256), 0, stream,
                       qkvw, projw, fc1w, fc2w, wsb);
    hipLaunchKernelGGL(k_attnproj, dim3(1024), dim3(256), 0, stream,
                       x, g1v, b1v, wsb + OFF_QKV, qkvb, relb, wsb + OFF_PROJ, projb, x1);
    hipLaunchKernelGGL(k_mlp, dim3(1024), dim3(256), 0, stream,
                       x1, g2v, b2v, wsb + OFF_FC1, fc1b, wsb + OFF_FC2, fc2b, x1);
}

// Round 14
// 489.769 us; speedup vs baseline: 1.5056x; 1.0487x over previous
//
#include <hip/hip_runtime.h>

typedef unsigned short u16;
typedef unsigned int   u32;
typedef __attribute__((ext_vector_type(8))) short bf16x8;
typedef __attribute__((ext_vector_type(4))) float f32x4;

#define L_TOK   16384
#define C_DIM   192
#define HID_DIM 768

// bf16 weight workspace layout (u16 offsets) -- ALL gemm weights are stored
// as 12KB stage tiles with the LDS bank-swizzle baked in (m173/T2 pattern):
//   [R cols][K k] tile:  q = r*K + (k ^ ((r & MASK) << 3))
//   K=64 -> MASK=7 (qkv, fc1);  K=32 -> MASK=3 (proj, fc2)
#define OFF_QKV  0          // 18 tiles (head*3+kc) of [96][64]   = 110592
#define OFF_PROJ 110592     //  6 tiles (head)      of [192][32]  =  36864
#define OFF_FC1  147456     // 24 tiles (hc*3+kc)   of [96][64]   = 147456
#define OFF_FC2  294912     // 24 tiles (hc*3+sc)   of [192][32]  = 147456
#define CVT_TOT  442368     // total u16 elements (884736 B)

union FragU { int4 i4; bf16x8 h8; };

#define MFMA_B16(a,b,c) __builtin_amdgcn_mfma_f32_16x16x32_bf16(a,b,c,0,0,0)

__device__ __forceinline__ u16 f2bf(float f) {
    u32 t; __builtin_memcpy(&t, &f, 4);
    t += 0x7FFFu + ((t >> 16) & 1u);
    return (u16)(t >> 16);
}

// ---------------------------------------------------------------------------
// Kernel 0 v4: f32 -> bf16 weight convert+transpose, SOURCE-coalesced,
// swizzled stage-tile output layouts for ALL four weight matrices.
// ---------------------------------------------------------------------------
__global__ __launch_bounds__(256) void k_cvt(
    const float* __restrict__ qkvw, const float* __restrict__ projw,
    const float* __restrict__ fc1w, const float* __restrict__ fc2w,
    u16* __restrict__ ws)
{
    const int i = blockIdx.x * 256 + threadIdx.x;
    if (i >= CVT_TOT) return;
    float v; int dst;
    if (i < OFF_PROJ) {                      // qkvw[k][col] -> qkv tiles
        const int k = i / 576, col = i % 576;
        const int grp = col / 192, rem = col % 192;
        const int head = rem >> 5, dim = rem & 31;
        v = qkvw[i];
        const int cc = grp * 32 + dim;
        const int kc = k >> 6, ko = k & 63;
        dst = OFF_QKV + (head * 3 + kc) * 6144 + cc * 64 + (ko ^ ((cc & 7) << 3));
    } else if (i < OFF_FC1) {                // projw[cin][cout] -> proj tiles
        const int s = i - OFF_PROJ;
        const int cin = s / 192, cout = s % 192;
        const int head = cin >> 5, j = cin & 31;
        v = projw[s];
        dst = OFF_PROJ + head * 6144 + cout * 32 + (j ^ ((cout & 3) << 3));
    } else if (i < OFF_FC2) {                // fc1w[k][h] -> fc1 tiles
        const int s = i - OFF_FC1;
        const int k = s / 768, h = s % 768;
        v = fc1w[s];
        const int hc = h / 96, cc = h % 96;
        const int kc = k >> 6, ko = k & 63;
        dst = OFF_FC1 + (hc * 3 + kc) * 6144 + cc * 64 + (ko ^ ((cc & 7) << 3));
    } else {                                 // fc2w[h][c] -> fc2 tiles
        const int s = i - OFF_FC2;
        const int h = s / 192, c = s % 192;
        v = fc2w[s];
        const int hc = h / 96, rem = h % 96;
        const int sc = rem >> 5, ho = rem & 31;
        dst = OFF_FC2 + (hc * 3 + sc) * 6144 + c * 32 + (ho ^ ((c & 3) << 3));
    }
    ws[dst] = f2bf(v);
}

// ---------------------------------------------------------------------------
// Kernel 1 v6: async gll weight staging, double-buffered 12KB stage tiles,
// 4 barriers/head (was 8). qsb/oh share one buffer (wave-private, disjoint
// in-order lifetimes). LDS: union(xw 51200, pw[2] 48128) + wdb 24576 +
// relbs 5400 = 81176 B -> 2 blocks/CU.
// ---------------------------------------------------------------------------
__global__ __launch_bounds__(256, 2) void k_attnproj(
    const float* __restrict__ x, const float* __restrict__ g1v, const float* __restrict__ b1v,
    const u16* __restrict__ qkvwT, const float* __restrict__ qkvb,
    const float* __restrict__ relb, const u16* __restrict__ projT, const float* __restrict__ projb,
    float* __restrict__ x1)
{
    struct PW {
        u16 qoh[64 * 40];                   //  5120 B  Q rows (B-out..C) / O rows (E..P)
        u16 ksb[64 * 40];                   //  5120 B  K rows  [tok][dim]
        u16 vsbT[32 * 72];                  //  4608 B  V^T     [dim][tok]
        u16 psb[64 * 72];                   //  9216 B  P       [tok][key]
    };                                      // 24064 B per window
    union SmemU {
        u16 xw[128 * 200];                  // 51200 B (phase A only, padded stride)
        PW pw[2];                           // 48128 B
    };
    __shared__ __align__(16) SmemU u;
    __shared__ __align__(16) u16 wdb[2][6144];   // 2 x 12288 B weight stage tiles
    __shared__ float relbs[225 * 6];             //  5400 B

    const int t  = threadIdx.x;
    const int lane = t & 63, w = t >> 6;
    const int win = w >> 1, half = w & 1;
    const int l15 = lane & 15, quad = lane >> 4;
    const int wi2 = blockIdx.x * 2 + win;
    const int b  = wi2 >> 8;
    const int hb = (wi2 >> 4) & 15;
    const int wb = wi2 & 15;
    const bool maskon = (hb == 15) || (wb == 15);
    const f32x4 zf = {0.f, 0.f, 0.f, 0.f};

    // ---- async stage-tile issue: stage st = head*4+sub -> wdb[st&1] ----
    auto issue_stage = [&](int st) {
        const int hs = st >> 2, sub = st & 3;
        const u16* src = (sub < 3) ? qkvwT + (hs * 3 + sub) * 6144
                                   : projT + hs * 6144;
        u16* dstb = &wdb[st & 1][0];
        #pragma unroll
        for (int c = 0; c < 3; ++c) {
            const int cid = c * 4 + w;            // 12 x 512-u16 chunks
            __builtin_amdgcn_global_load_lds(
                (const __attribute__((address_space(1))) void*)(src + cid * 512 + lane * 8),
                (__attribute__((address_space(3))) void*)(dstb + cid * 512),
                16, 0, 0);
        }
    };
    issue_stage(0);   // lands under the LN prologue

    for (int i = t; i < 225 * 6; i += 256) relbs[i] = relb[i];

    // ---- Phase A: LN1 for 128 tokens (both windows), 2 per quartet-thread ----
    #pragma unroll
    for (int tk = 0; tk < 2; ++tk) {
        const int nn = t >> 2, q4 = t & 3;
        const int tok = tk * 64 + nn;
        const int tw = tok >> 6, n = tok & 63;
        const int wiA = blockIdx.x * 2 + tw;
        const int bA  = wiA >> 8;
        const int hbA = (wiA >> 4) & 15, wbA = wiA & 15;
        const int r = n >> 3, c = n & 7;
        const int ho = (hbA * 8 + r + 4) & 127;
        const int wo = (wbA * 8 + c + 4) & 127;
        const size_t xoff = ((size_t)bA * L_TOK + ho * 128 + wo) * C_DIM;
        const float* xp = x + xoff + q4 * 48;
        float f[48];
        float sum = 0.f, sq = 0.f;
        #pragma unroll
        for (int i = 0; i < 12; ++i) {
            float4 v = *(const float4*)(xp + i * 4);
            f[i*4+0]=v.x; f[i*4+1]=v.y; f[i*4+2]=v.z; f[i*4+3]=v.w;
            sum += v.x+v.y+v.z+v.w;
            sq  += v.x*v.x + v.y*v.y + v.z*v.z + v.w*v.w;
        }
        sum += __shfl_xor(sum, 1); sum += __shfl_xor(sum, 2);
        sq  += __shfl_xor(sq, 1);  sq  += __shfl_xor(sq, 2);
        const float mu = sum * (1.f / 192.f);
        const float rstd = rsqrtf(sq * (1.f / 192.f) - mu * mu + 1e-5f);
        u16* xrow = u.xw + tok * 200 + q4 * 48;
        #pragma unroll
        for (int i = 0; i < 6; ++i) {
            u32 pk[4];
            #pragma unroll
            for (int j = 0; j < 4; ++j) {
                float g0 = g1v[q4*48 + i*8 + j*2],     b0 = b1v[q4*48 + i*8 + j*2];
                float g1 = g1v[q4*48 + i*8 + j*2 + 1], b1 = b1v[q4*48 + i*8 + j*2 + 1];
                float y0 = (f[i*8+j*2]   - mu) * rstd * g0 + b0;
                float y1 = (f[i*8+j*2+1] - mu) * rstd * g1 + b1;
                pk[j] = (u32)f2bf(y0) | (((u32)f2bf(y1)) << 16);
            }
            *(int4*)(xrow + i * 8) = make_int4((int)pk[0], (int)pk[1], (int)pk[2], (int)pk[3]);
        }
    }
    __syncthreads();

    FragU afrag[2][6];
    #pragma unroll
    for (int mt = 0; mt < 2; ++mt)
        #pragma unroll
        for (int kk = 0; kk < 6; ++kk)
            afrag[mt][kk].i4 = *(const int4*)(u.xw +
                (win*64 + half*32 + mt*16 + l15) * 200 + kk*32 + quad*8);
    // xw dead from here; first pw write (B-out) happens after >=3 barriers.

    PW* P = &u.pw[win];
    const int rb = half*32 + quad*4;

    f32x4 acc2[2][12];
    #pragma unroll
    for (int mt = 0; mt < 2; ++mt)
        #pragma unroll
        for (int nt = 0; nt < 12; ++nt) acc2[mt][nt] = zf;

    int g = 0;   // stage counter; stage g lives in wdb[g&1]
    for (int head = 0; head < 6; ++head) {
        // ---- Phase B: qkv via MFMA from gll-staged swizzled tiles ----
        f32x4 accq[2][6];
        #pragma unroll
        for (int mt = 0; mt < 2; ++mt)
            #pragma unroll
            for (int nt = 0; nt < 6; ++nt) accq[mt][nt] = zf;

        for (int kc = 0; kc < 3; ++kc) {
            __syncthreads();            // stage g ready (vmcnt drained); g-2 readers done
            issue_stage(g + 1);         // next kc tile or proj tile
            const u16* buf = &wdb[g & 1][0];
            #pragma unroll
            for (int s = 0; s < 2; ++s) {
                #pragma unroll
                for (int nt = 0; nt < 6; ++nt) {
                    const int row = nt*16 + l15;
                    FragU bf_;
                    bf_.i4 = *(const int4*)(buf + row*64 +
                                            ((s*32 + quad*8) ^ ((row & 7) << 3)));
                    accq[0][nt] = MFMA_B16(afrag[0][kc*2 + s].h8, bf_.h8, accq[0][nt]);
                    accq[1][nt] = MFMA_B16(afrag[1][kc*2 + s].h8, bf_.h8, accq[1][nt]);
                }
            }
            ++g;
        }
        // ---- B-out: store q/k row-major, v transposed (window buffers) ----
        #pragma unroll
        for (int mt = 0; mt < 2; ++mt) {
            #pragma unroll
            for (int nt = 0; nt < 6; ++nt) {
                const int grp = nt >> 1;
                const int dim = (nt & 1)*16 + l15;
                const float bias = qkvb[grp*192 + head*32 + dim];
                float vv[4];
                #pragma unroll
                for (int rg = 0; rg < 4; ++rg) vv[rg] = accq[mt][nt][rg] + bias;
                const int rowb = rb + mt*16;
                if (grp == 0) {
                    #pragma unroll
                    for (int rg = 0; rg < 4; ++rg)
                        P->qoh[(rowb + rg)*40 + dim] = f2bf(vv[rg] * 0.17677669529663687f);
                } else if (grp == 1) {
                    #pragma unroll
                    for (int rg = 0; rg < 4; ++rg)
                        P->ksb[(rowb + rg)*40 + dim] = f2bf(vv[rg]);
                } else {
                    u32 lo = (u32)f2bf(vv[0]) | (((u32)f2bf(vv[1])) << 16);
                    u32 hi = (u32)f2bf(vv[2]) | (((u32)f2bf(vv[3])) << 16);
                    *(uint2*)&P->vsbT[dim*72 + rowb] = make_uint2(lo, hi);
                }
            }
        }
        __syncthreads();   // B4: K/V visible; proj stage (g) drained
        if (head < 5) issue_stage(g + 1);   // next head's kc0, hidden under C..P

        // ---- Phase C: scores via MFMA ----
        FragU qf0, qf1;
        qf0.i4 = *(const int4*)(P->qoh + (half*32 + l15)*40 + quad*8);
        qf1.i4 = *(const int4*)(P->qoh + (half*32 + 16 + l15)*40 + quad*8);
        f32x4 sv[2][4];
        #pragma unroll
        for (int nt = 0; nt < 4; ++nt) {
            FragU kf; kf.i4 = *(const int4*)(P->ksb + (nt*16 + l15)*40 + quad*8);
            sv[0][nt] = MFMA_B16(qf0.h8, kf.h8, zf);
            sv[1][nt] = MFMA_B16(qf1.h8, kf.h8, zf);
        }
        const int kr_ = l15 >> 3, kc2 = l15 & 7;
        #pragma unroll
        for (int mt = 0; mt < 2; ++mt) {
            #pragma unroll
            for (int rg = 0; rg < 4; ++rg) {
                const int qm = rb + mt*16 + rg;
                const int qr = qm >> 3, qc = qm & 7;
                #pragma unroll
                for (int nt = 0; nt < 4; ++nt) {
                    const int kr = nt*2 + kr_;
                    sv[mt][nt][rg] += relbs[((qr - kr + 7)*15 + (qc - kc2 + 7))*6 + head];
                }
            }
        }
        if (maskon) {
            #pragma unroll
            for (int mt = 0; mt < 2; ++mt) {
                #pragma unroll
                for (int rg = 0; rg < 4; ++rg) {
                    const int qm = rb + mt*16 + rg;
                    const int qr = qm >> 3, qc = qm & 7;
                    const int regq = ((hb == 15) ? (qr < 4 ? 1 : 2) : 0) * 3
                                   + ((wb == 15) ? (qc < 4 ? 1 : 2) : 0);
                    #pragma unroll
                    for (int nt = 0; nt < 4; ++nt) {
                        const int kr = nt*2 + kr_;
                        const int regk = ((hb == 15) ? (kr < 4 ? 1 : 2) : 0) * 3
                                       + ((wb == 15) ? (kc2 < 4 ? 1 : 2) : 0);
                        if (regq != regk) sv[mt][nt][rg] -= 100.f;
                    }
                }
            }
        }
        // ---- Phase D: softmax ----
        #pragma unroll
        for (int mt = 0; mt < 2; ++mt) {
            #pragma unroll
            for (int rg = 0; rg < 4; ++rg) {
                float mx = fmaxf(fmaxf(sv[mt][0][rg], sv[mt][1][rg]),
                                 fmaxf(sv[mt][2][rg], sv[mt][3][rg]));
                mx = fmaxf(mx, __shfl_xor(mx, 1));
                mx = fmaxf(mx, __shfl_xor(mx, 2));
                mx = fmaxf(mx, __shfl_xor(mx, 4));
                mx = fmaxf(mx, __shfl_xor(mx, 8));
                float s0 = 0.f;
                #pragma unroll
                for (int nt = 0; nt < 4; ++nt) {
                    sv[mt][nt][rg] = __expf(sv[mt][nt][rg] - mx); s0 += sv[mt][nt][rg];
                }
                s0 += __shfl_xor(s0, 1); s0 += __shfl_xor(s0, 2);
                s0 += __shfl_xor(s0, 4); s0 += __shfl_xor(s0, 8);
                const float inv = 1.f / s0;
                #pragma unroll
                for (int nt = 0; nt < 4; ++nt)
                    P->psb[(rb + mt*16 + rg)*72 + nt*16 + l15] = f2bf(sv[mt][nt][rg] * inv);
            }
        }
        // psb wave-private -> no barrier around E.

        // ---- Phase E: P@V via MFMA; O -> qoh (qsb reads done, in-order LDS) ----
        FragU vb[2][2];
        #pragma unroll
        for (int ntv = 0; ntv < 2; ++ntv) {
            vb[ntv][0].i4 = *(const int4*)(P->vsbT + (ntv*16 + l15)*72 + quad*8);
            vb[ntv][1].i4 = *(const int4*)(P->vsbT + (ntv*16 + l15)*72 + 32 + quad*8);
        }
        #pragma unroll
        for (int mt = 0; mt < 2; ++mt) {
            FragU pa0, pa1;
            pa0.i4 = *(const int4*)(P->psb + (half*32 + mt*16 + l15)*72 + quad*8);
            pa1.i4 = *(const int4*)(P->psb + (half*32 + mt*16 + l15)*72 + 32 + quad*8);
            f32x4 ov0 = zf, ov1 = zf;
            ov0 = MFMA_B16(pa0.h8, vb[0][0].h8, ov0);
            ov0 = MFMA_B16(pa1.h8, vb[0][1].h8, ov0);
            ov1 = MFMA_B16(pa0.h8, vb[1][0].h8, ov1);
            ov1 = MFMA_B16(pa1.h8, vb[1][1].h8, ov1);
            #pragma unroll
            for (int rg = 0; rg < 4; ++rg) {
                P->qoh[(rb + mt*16 + rg)*40 + l15]      = f2bf(ov0[rg]);
                P->qoh[(rb + mt*16 + rg)*40 + 16 + l15] = f2bf(ov1[rg]);
            }
        }

        // ---- Phase P: proj via MFMA from gll-staged swizzled proj tile ----
        const u16* pbuf = &wdb[g & 1][0];
        FragU ao0, ao1;
        ao0.i4 = *(const int4*)(P->qoh + (half*32 + l15)*40 + quad*8);
        ao1.i4 = *(const int4*)(P->qoh + (half*32 + 16 + l15)*40 + quad*8);
        #pragma unroll
        for (int nt = 0; nt < 12; ++nt) {
            const int row = nt*16 + l15;
            FragU bp;
            bp.i4 = *(const int4*)(pbuf + row*32 + ((quad*8) ^ ((row & 3) << 3)));
            acc2[0][nt] = MFMA_B16(ao0.h8, bp.h8, acc2[0][nt]);
            acc2[1][nt] = MFMA_B16(ao1.h8, bp.h8, acc2[1][nt]);
        }
        ++g;
    }

    // ---- Phase F: + proj bias + residual, write x1 ----
    {
        float pb[12];
        #pragma unroll
        for (int nt = 0; nt < 12; ++nt) pb[nt] = projb[nt*16 + l15];
        #pragma unroll
        for (int mt = 0; mt < 2; ++mt) {
            #pragma unroll
            for (int rg = 0; rg < 4; ++rg) {
                const int tok = rb + mt*16 + rg;
                const int tr = tok >> 3, tc = tok & 7;
                const int ho2 = (hb * 8 + tr + 4) & 127;
                const int wo2 = (wb * 8 + tc + 4) & 127;
                const size_t base = ((size_t)b * L_TOK + ho2 * 128 + wo2) * C_DIM;
                #pragma unroll
                for (int nt = 0; nt < 12; ++nt) {
                    const int col = nt*16 + l15;
                    x1[base + col] = acc2[mt][nt][rg] + pb[nt] + x[base + col];
                }
            }
        }
    }
}

// ---------------------------------------------------------------------------
// Kernel 2 v10 (R13, unchanged): async gll weight staging, double-buffered
// 12KB stage tiles, swizzle baked into ws. LDS 51.2KB.
// ---------------------------------------------------------------------------
__global__ __launch_bounds__(256, 2) void k_mlp(
    const float* x1, const float* __restrict__ g2v, const float* __restrict__ b2v,
    const u16* __restrict__ fc1wT, const float* __restrict__ fc1b,
    const u16* __restrict__ fc2wT, const float* __restrict__ fc2b,
    float* out)
{
    union SmemU {
        u16 xnA[64 * 200];     // 25600 B  LN2'd tokens, one half at a time (prologue)
        u16 hbuf[128 * 104];   // 26624 B  GELU'd hidden chunk (xnA dead by then)
    };
    __shared__ __align__(16) SmemU u;
    __shared__ __align__(16) u16 wbig[2][6144];   // 2 x 12288 B stage tiles

    const int blk = blockIdx.x;
    const int t = threadIdx.x;
    const size_t row0 = (size_t)blk * 128;
    const int lane = t & 63, w = t >> 6;
    const int l15 = lane & 15, quad = lane >> 4;
    const f32x4 zf = {0.f, 0.f, 0.f, 0.f};

    auto issue_stage = [&](int st) {
        const int hcs = st / 6, sub = st % 6;
        const u16* src = (sub < 3) ? fc1wT + (hcs * 3 + sub) * 6144
                                   : fc2wT + (hcs * 3 + (sub - 3)) * 6144;
        u16* dstb = &wbig[st & 1][0];
        #pragma unroll
        for (int c = 0; c < 3; ++c) {
            const int cid = c * 4 + w;
            __builtin_amdgcn_global_load_lds(
                (const __attribute__((address_space(1))) void*)(src + cid * 512 + lane * 8),
                (__attribute__((address_space(3))) void*)(dstb + cid * 512),
                16, 0, 0);
        }
    };
    issue_stage(0);

    FragU afrag[2][6];
    for (int hf = 0; hf < 2; ++hf) {
        const int nn = t >> 2, q4 = t & 3;
        const int tok = hf * 64 + nn;
        const float* xp = x1 + (row0 + tok) * C_DIM + q4 * 48;
        float f[48];
        float sum = 0.f, sq = 0.f;
        #pragma unroll
        for (int i = 0; i < 12; ++i) {
            float4 v = *(const float4*)(xp + i * 4);
            f[i*4+0]=v.x; f[i*4+1]=v.y; f[i*4+2]=v.z; f[i*4+3]=v.w;
            sum += v.x+v.y+v.z+v.w;
            sq  += v.x*v.x + v.y*v.y + v.z*v.z + v.w*v.w;
        }
        sum += __shfl_xor(sum,1); sum += __shfl_xor(sum,2);
        sq  += __shfl_xor(sq,1);  sq  += __shfl_xor(sq,2);
        const float mu = sum * (1.f/192.f);
        const float rstd = rsqrtf(sq * (1.f/192.f) - mu*mu + 1e-5f);
        u16* xrow = u.xnA + nn * 200 + q4 * 48;
        #pragma unroll
        for (int i = 0; i < 6; ++i) {
            u32 pk[4];
            #pragma unroll
            for (int j = 0; j < 4; ++j) {
                float g0 = g2v[q4*48 + i*8 + j*2],     b0 = b2v[q4*48 + i*8 + j*2];
                float g1 = g2v[q4*48 + i*8 + j*2 + 1], b1 = b2v[q4*48 + i*8 + j*2 + 1];
                float y0 = (f[i*8+j*2]   - mu) * rstd * g0 + b0;
                float y1 = (f[i*8+j*2+1] - mu) * rstd * g1 + b1;
                pk[j] = (u32)f2bf(y0) | (((u32)f2bf(y1)) << 16);
            }
            *(int4*)(xrow + i*8) = make_int4((int)pk[0], (int)pk[1], (int)pk[2], (int)pk[3]);
        }
        __syncthreads();
        #pragma unroll
        for (int kk = 0; kk < 6; ++kk)
            afrag[hf][kk].i4 = *(const int4*)(u.xnA + (w*16 + l15) * 200 + kk*32 + quad*8);
        __syncthreads();
    }

    f32x4 acc2[2][12];
    #pragma unroll
    for (int mt = 0; mt < 2; ++mt)
        #pragma unroll
        for (int nt = 0; nt < 12; ++nt) acc2[mt][nt] = zf;

    int g = 0;
    for (int hc = 0; hc < 8; ++hc) {
        f32x4 acc1[2][6];
        #pragma unroll
        for (int mt = 0; mt < 2; ++mt)
            #pragma unroll
            for (int nt = 0; nt < 6; ++nt) acc1[mt][nt] = zf;

        for (int kc = 0; kc < 3; ++kc) {
            __syncthreads();
            if (g < 47) issue_stage(g + 1);
            const u16* buf = &wbig[g & 1][0];
            #pragma unroll
            for (int s = 0; s < 2; ++s) {
                #pragma unroll
                for (int nt = 0; nt < 6; ++nt) {
                    const int row = nt*16 + l15;
                    FragU bf_;
                    bf_.i4 = *(const int4*)(buf + row*64 +
                                            ((s*32 + quad*8) ^ ((row & 7) << 3)));
                    acc1[0][nt] = MFMA_B16(afrag[0][kc*2 + s].h8, bf_.h8, acc1[0][nt]);
                    acc1[1][nt] = MFMA_B16(afrag[1][kc*2 + s].h8, bf_.h8, acc1[1][nt]);
                }
            }
            ++g;
        }
        #pragma unroll
        for (int nt = 0; nt < 6; ++nt) {
            const float bb = fc1b[hc*96 + nt*16 + l15];
            #pragma unroll
            for (int mt = 0; mt < 2; ++mt) {
                #pragma unroll
                for (int rg = 0; rg < 4; ++rg) {
                    float h = acc1[mt][nt][rg] + bb;
                    float e = __expf(h * (-1.5957691216057308f
                                          - 0.0713548162726302f * h * h));
                    float gl = h / (1.f + e);
                    u.hbuf[(mt*64 + w*16 + quad*4 + rg) * 104 + nt*16 + l15] = f2bf(gl);
                }
            }
        }
        for (int sc = 0; sc < 3; ++sc) {
            __syncthreads();
            if (g < 47) issue_stage(g + 1);
            const u16* buf = &wbig[g & 1][0];
            FragU ha0, ha1;
            ha0.i4 = *(const int4*)(u.hbuf + (w*16 + l15) * 104 + sc*32 + quad*8);
            ha1.i4 = *(const int4*)(u.hbuf + (64 + w*16 + l15) * 104 + sc*32 + quad*8);
            #pragma unroll
            for (int nt = 0; nt < 12; ++nt) {
                const int row = nt*16 + l15;
                FragU bf_;
                bf_.i4 = *(const int4*)(buf + row*32 +
                                        ((quad*8) ^ ((row & 3) << 3)));
                acc2[0][nt] = MFMA_B16(ha0.h8, bf_.h8, acc2[0][nt]);
                acc2[1][nt] = MFMA_B16(ha1.h8, bf_.h8, acc2[1][nt]);
            }
            ++g;
        }
    }

    #pragma unroll
    for (int nt = 0; nt < 12; ++nt) {
        const int col = nt*16 + l15;
        const float bb = fc2b[col];
        #pragma unroll
        for (int mt = 0; mt < 2; ++mt) {
            #pragma unroll
            for (int rg = 0; rg < 4; ++rg) {
                const size_t idx = (row0 + mt*64 + w*16 + quad*4 + rg) * C_DIM + col;
                out[idx] = acc2[mt][nt][rg] + bb + x1[idx];
            }
        }
    }
}

extern "C" void kernel_launch(void* const* d_in, const int* in_sizes, int n_in,
                              void* d_out, int out_size, void* d_ws, size_t ws_size,
                              hipStream_t stream) {
    const float* x     = (const float*)d_in[0];
    // d_in[1]=h, d_in[2]=w (ints, fixed 128 -> hardcoded)
    const float* g1v   = (const float*)d_in[3];
    const float* b1v   = (const float*)d_in[4];
    const float* qkvw  = (const float*)d_in[5];
    const float* qkvb  = (const float*)d_in[6];
    const float* projw = (const float*)d_in[7];
    const float* projb = (const float*)d_in[8];
    const float* relb  = (const float*)d_in[9];
    const float* g2v   = (const float*)d_in[10];
    const float* b2v   = (const float*)d_in[11];
    const float* fc1w  = (const float*)d_in[12];
    const float* fc1b  = (const float*)d_in[13];
    const float* fc2w  = (const float*)d_in[14];
    const float* fc2b  = (const float*)d_in[15];

    float* x1 = (float*)d_out;
    u16* wsb  = (u16*)d_ws;      // 884736 B of bf16 weights

    hipLaunchKernelGGL(k_cvt, dim3((CVT_TOT + 255) / 256), dim3(256), 0, stream,
                       qkvw, projw, fc1w, fc2w, wsb);
    hipLaunchKernelGGL(k_attnproj, dim3(1024), dim3(256), 0, stream,
                       x, g1v, b1v, wsb + OFF_QKV, qkvb, relb, wsb + OFF_PROJ, projb, x1);
    hipLaunchKernelGGL(k_mlp, dim3(1024), dim3(256), 0, stream,
                       x1, g2v, b2v, wsb + OFF_FC1, fc1b, wsb + OFF_FC2, fc2b, x1);
}